// Round 3
// baseline (429.887 us; speedup 1.0000x reference)
//
#include <hip/hip_runtime.h>

// QuantumAttentionMechanism on MI355X (gfx950)
// B=2, L=2048, D=1024, H=16, hd=64, Q=8.
//
// Algebra: combined score = ((1-ent)*Qh.Kh + ent^2*(w*cos qq).cos kq + ent^2*(w*sin qq).sin kq)/8
//          -> single 96-dim (80 used) bf16 GEMM over augmented Q~/K~ rows.
// R9: k_flash = R6's proven deep-prefetch structure (reg-staged K dbuf, depth-2 K
//     prefetch, V frags prefetched 1 iter ahead, padded [64][104]) + 16 rows/wave
//     i-tile 64 grid(32,16,2) for 4 blocks/CU, + exp2-direct (log2e folded into K~
//     in k_features), v_cvt_pk_bf16_f32 pack, setprio. R8's shallow same-iter
//     prefetch (gload_lds + V same-iter) exposed L3 latency at every barrier -> reverted.
// Workspace layout (bytes), total ~92.8 MB:
//   Xq 0  Xk 8388608  Xv 16777216 | Wqb 25165824 Wkb 27262976 Wvb 29360128 Wob 31457280
//   Qp 33554432 Kp 41943040 VtG 50331648 | Qa 58720256 Ka 71303168
//   (unused) 83886080 lbuf 84148224 | At 84410368  (end 92798976)

typedef unsigned short u16;
typedef unsigned int u32;
typedef short v8s __attribute__((ext_vector_type(8)));
typedef float v4f __attribute__((ext_vector_type(4)));

static __device__ __forceinline__ float b2f(u16 h) {
  union { u32 u; float f; } a; a.u = ((u32)h) << 16; return a.f;
}
static __device__ __forceinline__ u16 f2b(float f) {
  union { float f; u32 u; } a; a.f = f;
  u32 u = a.u;
  u32 r = u + 0x7FFFu + ((u >> 16) & 1u);  // RNE
  return (u16)(r >> 16);
}
static __device__ __forceinline__ v4f mfma16(v8s a, v8s b, v4f c) {
  return __builtin_amdgcn_mfma_f32_16x16x32_bf16(a, b, c, 0, 0, 0);
}
// async global->LDS, 16B per lane; LDS dest = wave-uniform base + lane*16
static __device__ __forceinline__ void gload16(const u16* g, u16* l) {
  __builtin_amdgcn_global_load_lds((const __attribute__((address_space(1))) u32*)g,
                                   (__attribute__((address_space(3))) u32*)l, 16, 0, 0);
}
// 2^x via the native transcendental (scores are pre-scaled by log2(e))
static __device__ __forceinline__ float exp2fast(float x) {
  float r; asm("v_exp_f32 %0, %1" : "=v"(r) : "v"(x)); return r;
}
// pack two f32 -> [bf16(hi)|bf16(lo)]
static __device__ __forceinline__ u32 cvtpk_bf16(float lo, float hi) {
  u32 r; asm("v_cvt_pk_bf16_f32 %0, %1, %2" : "=v"(r) : "v"(lo), "v"(hi)); return r;
}

// ---------------- fused fp32 -> bf16 convert (all 7 arrays; dst region contiguous) ----------
__global__ __launch_bounds__(256) void k_f2b_all(const float* __restrict__ q, const float* __restrict__ k,
                                                 const float* __restrict__ v, const float* __restrict__ wq,
                                                 const float* __restrict__ wk, const float* __restrict__ wv,
                                                 const float* __restrict__ wo, u16* __restrict__ y) {
  int i = blockIdx.x * 256 + threadIdx.x;  // group of 4 elems; 4194304 total
  const float* src; int off;
  if (i < 1048576)      { src = q;  off = i; }
  else if (i < 2097152) { src = k;  off = i - 1048576; }
  else if (i < 3145728) { src = v;  off = i - 2097152; }
  else if (i < 3407872) { src = wq; off = i - 3145728; }
  else if (i < 3670016) { src = wk; off = i - 3407872; }
  else if (i < 3932160) { src = wv; off = i - 3670016; }
  else                  { src = wo; off = i - 3932160; }
  float4 val = ((const float4*)src)[off];
  union { u16 s[4]; uint2 u; } o;
  o.s[0] = f2b(val.x); o.s[1] = f2b(val.y); o.s[2] = f2b(val.z); o.s[3] = f2b(val.w);
  ((uint2*)y)[i] = o.u;
}

// ---------------- 128x128xBK64 GEMM, C = A[M,K]*B[N,K]^T + bias (M=4096,N=K=1024) --------
// BK=64 stored as two 32-elem halves (each the m97 conflict-free unpadded layout).
// blockIdx.z selects operand set. Epilogue: Cf -> fp32 rm; z<2 -> bf16 rm; z==2 -> V^T via LDS.
__global__ __launch_bounds__(256) void k_gemm128(
    const u16* __restrict__ A0, const u16* __restrict__ A1, const u16* __restrict__ A2,
    const u16* __restrict__ B0, const u16* __restrict__ B1, const u16* __restrict__ B2,
    const float* __restrict__ bias0, const float* __restrict__ bias1, const float* __restrict__ bias2,
    u16* __restrict__ O0, u16* __restrict__ O1, u16* __restrict__ O2t,
    float* __restrict__ Cf) {
  __shared__ __align__(16) u16 pool[18432];  // 36.9 KB: As|Bs (32KB) / Ts (34.8KB) aliased
  u16* As = pool;             // [kk][row][32] : kk*4096 + row*32 + c
  u16* Bs = pool + 8192;
  const int K = 1024, N = 1024;
  int t = threadIdx.x, w = t >> 6, lane = t & 63, quad = lane >> 4, l16 = lane & 15;
  int z = blockIdx.z;
  const u16* A = (z == 0) ? A0 : (z == 1) ? A1 : A2;
  const u16* Bm = (z == 0) ? B0 : (z == 1) ? B1 : B2;
  const float* bias = (z == 0) ? bias0 : (z == 1) ? bias1 : bias2;
  int n0 = blockIdx.x * 128, m0 = blockIdx.y * 128;

  // staging: 8 instrs/wave; q: mat=q>>2, kk=(q>>1)&1, rowgroup g=w+(q&1)*4
  int srow = lane >> 2, scol = (lane & 3) * 8;
  const u16* gp[8]; u16* lp[8];
#pragma unroll
  for (int qi = 0; qi < 8; ++qi) {
    int mat = qi >> 2, kk = (qi >> 1) & 1, g = w + (qi & 1) * 4;
    int row = g * 16 + srow;
    gp[qi] = (mat ? Bm + (size_t)(n0 + row) * K : A + (size_t)(m0 + row) * K) + kk * 32 + scol;
    lp[qi] = (mat ? Bs : As) + kk * 4096 + g * 512;
  }

  int mrow = (w >> 1) * 64, ncol = (w & 1) * 64;
  v4f zf = {0.f, 0.f, 0.f, 0.f};
  v4f acc[4][4];
#pragma unroll
  for (int mi = 0; mi < 4; ++mi)
#pragma unroll
    for (int ni = 0; ni < 4; ++ni) acc[mi][ni] = zf;

  for (int k0 = 0; k0 < K; k0 += 64) {
    __syncthreads();
#pragma unroll
    for (int qi = 0; qi < 8; ++qi) gload16(gp[qi] + k0, lp[qi]);
    __syncthreads();  // drains vmcnt
#pragma unroll
    for (int kk = 0; kk < 2; ++kk) {
      v8s af[4], bfr[4];
#pragma unroll
      for (int x = 0; x < 4; ++x) {
        af[x] = *(const v8s*)&As[kk * 4096 + (mrow + x * 16 + l16) * 32 + quad * 8];
        bfr[x] = *(const v8s*)&Bs[kk * 4096 + (ncol + x * 16 + l16) * 32 + quad * 8];
      }
#pragma unroll
      for (int mi = 0; mi < 4; ++mi)
#pragma unroll
        for (int ni = 0; ni < 4; ++ni)
          acc[mi][ni] = mfma16(af[mi], bfr[ni], acc[mi][ni]);
    }
  }

  float bv[4];
#pragma unroll
  for (int ni = 0; ni < 4; ++ni) bv[ni] = bias[n0 + ncol + ni * 16 + l16];

  if (Cf) {
#pragma unroll
    for (int mi = 0; mi < 4; ++mi)
#pragma unroll
      for (int ni = 0; ni < 4; ++ni)
#pragma unroll
        for (int r = 0; r < 4; ++r)
          Cf[(size_t)(m0 + mrow + mi * 16 + quad * 4 + r) * N + n0 + ncol + ni * 16 + l16] =
              acc[mi][ni][r] + bv[ni];
  } else if (z != 2) {
    u16* O = z ? O1 : O0;
#pragma unroll
    for (int mi = 0; mi < 4; ++mi)
#pragma unroll
      for (int ni = 0; ni < 4; ++ni)
#pragma unroll
        for (int r = 0; r < 4; ++r)
          O[(size_t)(m0 + mrow + mi * 16 + quad * 4 + r) * N + n0 + ncol + ni * 16 + l16] =
              f2b(acc[mi][ni][r] + bv[ni]);
  } else {
    // V^T: reuse pool as Ts[w][64][68]; wave-local write/read (same-wave DS order)
    __syncthreads();  // everyone done with As/Bs
    u16* Ts = pool + w * 64 * 68;
#pragma unroll
    for (int mi = 0; mi < 4; ++mi)
#pragma unroll
      for (int ni = 0; ni < 4; ++ni)
#pragma unroll
        for (int r = 0; r < 4; ++r)
          Ts[(mi * 16 + quad * 4 + r) * 68 + ni * 16 + l16] = f2b(acc[mi][ni][r] + bv[ni]);
    int c = lane;
    union { uint4 u[8]; u16 s[64]; } cb;
#pragma unroll
    for (int e = 0; e < 64; ++e) cb.s[e] = Ts[e * 68 + c];
    int bb = m0 >> 11, ml = m0 & 2047;
    u16* dst = O2t + ((size_t)(bb * 1024 + n0 + ncol + c)) * 2048 + ml + mrow;
#pragma unroll
    for (int e = 0; e < 8; ++e) *(uint4*)(dst + e * 8) = cb.u[e];
  }
}

// ---------------- build augmented Q~/K~ rows [B,H,L,96]; fused Q+K via blockIdx.y --------
// K-side scale carries log2(e) so the flash/pass2 exponential is a single v_exp_f32.
__global__ __launch_bounds__(256) void k_features(const u16* __restrict__ Qp, const u16* __restrict__ Kp,
                                                  const float* __restrict__ Wf, const float* __restrict__ bff,
                                                  const float* __restrict__ qw, const float* __restrict__ entp,
                                                  u16* __restrict__ Qaa, u16* __restrict__ Kaa) {
  int isK = blockIdx.y;
  const u16* P = isK ? Kp : Qp;
  u16* Out = isK ? Kaa : Qaa;
  int idx = blockIdx.x * 256 + threadIdx.x;  // 0..65535 = b*H*L + h*L + l
  int b = idx >> 15, h = (idx >> 11) & 15, l = idx & 2047;
  const u16* src = P + ((size_t)(b * 2048 + l)) * 1024 + h * 64;
  u16* dst = Out + (size_t)idx * 96;
  const float4* Wf4 = (const float4*)Wf;

  float x[64];
#pragma unroll
  for (int g = 0; g < 8; ++g) {
    union { uint4 u; u16 s[8]; } uu;
    uu.u = *(const uint4*)(src + g * 8);
#pragma unroll
    for (int e = 0; e < 8; ++e) x[g * 8 + e] = b2f(uu.s[e]);
  }
  float qv[8];
#pragma unroll
  for (int qq = 0; qq < 8; ++qq) qv[qq] = bff[qq];
#pragma unroll
  for (int d = 0; d < 64; ++d) {
    float4 wa = Wf4[d * 2], wb = Wf4[d * 2 + 1];
    float xd = x[d];
    qv[0] += xd * wa.x; qv[1] += xd * wa.y; qv[2] += xd * wa.z; qv[3] += xd * wa.w;
    qv[4] += xd * wb.x; qv[5] += xd * wb.y; qv[6] += xd * wb.z; qv[7] += xd * wb.w;
  }
  float cs[8], sn[8];
#pragma unroll
  for (int qq = 0; qq < 8; ++qq) {
    float e2 = __expf(2.f * qv[qq]);
    float th = 1.f - 2.f / (e2 + 1.f);  // tanh
    __sincosf(th, &sn[qq], &cs[qq]);
  }
  float ent = 1.f / (1.f + __expf(-entp[0]));
  union { uint4 u; u16 s[8]; } pc, ps;
  if (!isK) {
#pragma unroll
    for (int g = 0; g < 8; ++g) *(uint4*)(dst + g * 8) = *(const uint4*)(src + g * 8);
#pragma unroll
    for (int qq = 0; qq < 8; ++qq) {
      float sw = 1.f / (1.f + __expf(-qw[h * 8 + qq]));
      pc.s[qq] = f2b(cs[qq] * sw);
      ps.s[qq] = f2b(sn[qq] * sw);
    }
  } else {
    const float LOG2E = 1.44269504088896f;
    float c1 = (1.f - ent) * 0.125f * LOG2E, c2 = ent * ent * 0.125f * LOG2E;
#pragma unroll
    for (int g = 0; g < 8; ++g) {
      union { uint4 u; u16 s[8]; } ob;
#pragma unroll
      for (int e = 0; e < 8; ++e) ob.s[e] = f2b(x[g * 8 + e] * c1);
      *(uint4*)(dst + g * 8) = ob.u;
    }
#pragma unroll
    for (int qq = 0; qq < 8; ++qq) {
      pc.s[qq] = f2b(cs[qq] * c2);
      ps.s[qq] = f2b(sn[qq] * c2);
    }
  }
  *(uint4*)(dst + 64) = pc.u;
  *(uint4*)(dst + 72) = ps.u;
  uint4 z4 = {0, 0, 0, 0};
  *(uint4*)(dst + 80) = z4;
  *(uint4*)(dst + 88) = z4;
}

// ---------------- flash pass 1 (S^T, no-max): 4 waves x 16 i-rows, i-tile 64 ----------
// R6 deep-prefetch structure: K reg-staged dbuf (depth-2 tile prefetch), V frags
// prefetched 1 iter ahead from global/L2, padded [64][104] K tile, 1 barrier/iter.
// exp2-direct + cvt_pk pack + setprio on MFMA clusters.
__global__ __launch_bounds__(256) void k_flash(const u16* __restrict__ Qa, const u16* __restrict__ Ka,
                                               const u16* __restrict__ VtG, u16* __restrict__ At,
                                               float* __restrict__ lb) {
  __shared__ __align__(16) u16 Ks[2][64][104];   // double-buffered K~ tile [j][k]
  __shared__ __align__(16) u16 Ps[4][16][72];    // per-wave P [i(l16)][j]

  int t = threadIdx.x, w = t >> 6, lane = t & 63, quad = lane >> 4, l16 = lane & 15;
  int i0 = blockIdx.x * 64, h = blockIdx.y, b = blockIdx.z;
  size_t qbase = ((size_t)(b * 16 + h)) * 2048 * 96;
  v8s aq[3];
  {
    const u16* Qrow = Qa + qbase + (size_t)(i0 + w * 16 + l16) * 96;
#pragma unroll
    for (int ks = 0; ks < 3; ++ks) aq[ks] = *(const v8s*)(Qrow + ks * 32 + quad * 8);
  }
  const u16* Kbase = Ka + qbase;
  const u16* Vbase = VtG + ((size_t)(b * 1024 + h * 64)) * 2048;

  // K staging: 64x96 = 768 16B-groups, 3/thread
  const u16* kg[3]; int kdo[3];
#pragma unroll
  for (int p = 0; p < 3; ++p) {
    int idx = t + p * 256, r_ = idx / 12, c_ = idx % 12;
    kg[p] = Kbase + (size_t)r_ * 96 + c_ * 8;
    kdo[p] = r_ * 104 + c_ * 8;
  }
  u16* ks0 = &Ks[0][0][0];
  u16* ks1 = &Ks[1][0][0];

  v4f zf = {0.f, 0.f, 0.f, 0.f};
  v4f oacc[4] = {zf, zf, zf, zf};
  float l_acc = 0.f;

  // prologue: stage j=0 into buf0; regs hold j=64; V frags for j=0
  uint4 fk0 = *(const uint4*)kg[0];
  uint4 fk1 = *(const uint4*)kg[1];
  uint4 fk2 = *(const uint4*)kg[2];
  kg[0] += 6144; kg[1] += 6144; kg[2] += 6144;
  *(uint4*)(ks0 + kdo[0]) = fk0;
  *(uint4*)(ks0 + kdo[1]) = fk1;
  *(uint4*)(ks0 + kdo[2]) = fk2;
  fk0 = *(const uint4*)kg[0];
  fk1 = *(const uint4*)kg[1];
  fk2 = *(const uint4*)kg[2];
  kg[0] += 6144; kg[1] += 6144; kg[2] += 6144;
  v8s vf[8];
#pragma unroll
  for (int idx = 0; idx < 8; ++idx)
    vf[idx] = *(const v8s*)(Vbase + (size_t)((idx >> 1) * 16 + l16) * 2048 + (idx & 1) * 32 + quad * 8);
  __syncthreads();

  for (int j0 = 0; j0 < 2048; j0 += 64) {
    int cur = (j0 >> 6) & 1;
    const u16* kb = cur ? ks1 : ks0;
    u16* kw = cur ? ks0 : ks1;
    bool more = (j0 + 64) < 2048;
    if (more) {  // write next tile (regs) into alternate buffer
      *(uint4*)(kw + kdo[0]) = fk0;
      *(uint4*)(kw + kdo[1]) = fk1;
      *(uint4*)(kw + kdo[2]) = fk2;
    }
    if (j0 + 128 < 2048) {  // prefetch next-next K tile
      fk0 = *(const uint4*)kg[0];
      fk1 = *(const uint4*)kg[1];
      fk2 = *(const uint4*)kg[2];
      kg[0] += 6144; kg[1] += 6144; kg[2] += 6144;
    }
    v8s vn[8];
    if (more) {  // prefetch next V frags (global/L2)
#pragma unroll
      for (int idx = 0; idx < 8; ++idx)
        vn[idx] = *(const v8s*)(Vbase + (size_t)((idx >> 1) * 16 + l16) * 2048 + j0 + 64 +
                                (idx & 1) * 32 + quad * 8);
    }

    // S^T: sacc[j16] row=j(quad*4+r), col=i(l16)
    v4f sacc[4] = {zf, zf, zf, zf};
    __builtin_amdgcn_s_setprio(1);
#pragma unroll
    for (int j16 = 0; j16 < 4; ++j16)
#pragma unroll
      for (int ks = 0; ks < 3; ++ks) {
        v8s kf = *(const v8s*)(kb + (j16 * 16 + l16) * 104 + ks * 32 + quad * 8);
        sacc[j16] = mfma16(kf, aq[ks], sacc[j16]);
      }
    __builtin_amdgcn_s_setprio(0);

    // exp2 (scores pre-scaled by log2e) + row-sum + pack via cvt_pk
#pragma unroll
    for (int j16 = 0; j16 < 4; ++j16) {
      float e0 = exp2fast(sacc[j16][0]);
      float e1 = exp2fast(sacc[j16][1]);
      float e2 = exp2fast(sacc[j16][2]);
      float e3 = exp2fast(sacc[j16][3]);
      l_acc += (e0 + e1) + (e2 + e3);
      uint2 pp;
      pp.x = cvtpk_bf16(e0, e1);
      pp.y = cvtpk_bf16(e2, e3);
      *(uint2*)&Ps[w][l16][j16 * 16 + quad * 4] = pp;
    }

    // PV: P from per-wave LDS (same-wave DS order), V from registers
    __builtin_amdgcn_s_setprio(1);
#pragma unroll
    for (int jh = 0; jh < 2; ++jh) {
      v8s pf = *(const v8s*)&Ps[w][l16][jh * 32 + quad * 8];
#pragma unroll
      for (int d16 = 0; d16 < 4; ++d16)
        oacc[d16] = mfma16(pf, vf[d16 * 2 + jh], oacc[d16]);
    }
    __builtin_amdgcn_s_setprio(0);
    if (more) {
#pragma unroll
      for (int idx = 0; idx < 8; ++idx) vf[idx] = vn[idx];
      __syncthreads();
    }
  }

  // epilogue: row-sum reduce across quads, normalize, store
  l_acc += __shfl_xor(l_acc, 16, 64);
  l_acc += __shfl_xor(l_acc, 32, 64);
  float linv = 1.f / l_acc;
#pragma unroll
  for (int r = 0; r < 4; ++r) {
    float li = __shfl(linv, quad * 4 + r, 64);
    int ri = i0 + w * 16 + quad * 4 + r;
#pragma unroll
    for (int d16 = 0; d16 < 4; ++d16)
      At[((size_t)(b * 2048 + ri)) * 1024 + h * 64 + d16 * 16 + l16] = f2b(oacc[d16][r] * li);
  }
  if (lane < 16) {
    size_t mbase = ((size_t)(b * 16 + h)) * 2048;
    lb[mbase + i0 + w * 16 + lane] = l_acc;
  }
}

// ---------------- pass 2: attn.mean over heads -> out1[B,L,L] ----------------
__global__ __launch_bounds__(256) void k_pass2(const u16* __restrict__ Qa, const u16* __restrict__ Ka,
                                               const float* __restrict__ lb,
                                               float* __restrict__ out1) {
  __shared__ __align__(16) u16 Ks[64][104];
  __shared__ float Ls[16][128];
  int t = threadIdx.x, w = t >> 6, lane = t & 63, quad = lane >> 4, l16 = lane & 15;
  int j0 = blockIdx.x * 64, i0 = blockIdx.y * 128, b = blockIdx.z;

#pragma unroll
  for (int rep = 0; rep < 8; ++rep) {
    int idx = t + rep * 256;
    int hh = idx >> 7, il = idx & 127;
    Ls[hh][il] = 0.0625f / lb[((size_t)(b * 16 + hh)) * 2048 + i0 + il];
  }

  size_t base0 = (size_t)b * 16 * 2048 * 96;
  const u16* kg[3]; u16* kd[3];
#pragma unroll
  for (int rep = 0; rep < 3; ++rep) {
    int idx = t + rep * 256;
    int r_ = idx / 12, c_ = idx % 12;
    kg[rep] = Ka + base0 + (size_t)(j0 + r_) * 96 + c_ * 8;
    kd[rep] = &Ks[r_][c_ * 8];
  }
  uint4 f0 = *(const uint4*)kg[0];
  uint4 f1 = *(const uint4*)kg[1];
  uint4 f2 = *(const uint4*)kg[2];

  const u16* q0 = Qa + base0 + (size_t)(i0 + w * 32 + l16) * 96 + quad * 8;
  const u16* q1 = q0 + 16 * 96;

  v4f zf = {0.f, 0.f, 0.f, 0.f};
  v4f macc[2][4];
#pragma unroll
  for (int i16 = 0; i16 < 2; ++i16)
#pragma unroll
    for (int j16 = 0; j16 < 4; ++j16) macc[i16][j16] = zf;

  v8s a[2][3];
#pragma unroll
  for (int ks = 0; ks < 3; ++ks) {
    a[0][ks] = *(const v8s*)(q0 + ks * 32);
    a[1][ks] = *(const v8s*)(q1 + ks * 32);
  }

  for (int h = 0; h < 16; ++h) {
    *(uint4*)kd[0] = f0;
    *(uint4*)kd[1] = f1;
    *(uint4*)kd[2] = f2;
    __syncthreads();
    if (h < 15) {
      kg[0] += 196608; kg[1] += 196608; kg[2] += 196608;
      f0 = *(const uint4*)kg[0];
      f1 = *(const uint4*)kg[1];
      f2 = *(const uint4*)kg[2];
    }

    v4f sacc[2][4];
#pragma unroll
    for (int i16 = 0; i16 < 2; ++i16)
#pragma unroll
      for (int j16 = 0; j16 < 4; ++j16) sacc[i16][j16] = zf;
#pragma unroll
    for (int ks = 0; ks < 3; ++ks)
#pragma unroll
      for (int j16 = 0; j16 < 4; ++j16) {
        v8s kf = *(const v8s*)&Ks[j16 * 16 + l16][ks * 32 + quad * 8];
        sacc[0][j16] = mfma16(a[0][ks], kf, sacc[0][j16]);
        sacc[1][j16] = mfma16(a[1][ks], kf, sacc[1][j16]);
      }

    if (h < 15) {
      q0 += 196608; q1 += 196608;
#pragma unroll
      for (int ks = 0; ks < 3; ++ks) {
        a[0][ks] = *(const v8s*)(q0 + ks * 32);
        a[1][ks] = *(const v8s*)(q1 + ks * 32);
      }
    }

    float li[2][4];
#pragma unroll
    for (int i16 = 0; i16 < 2; ++i16)
#pragma unroll
      for (int r = 0; r < 4; ++r)
        li[i16][r] = Ls[h][w * 32 + i16 * 16 + quad * 4 + r];
#pragma unroll
    for (int i16 = 0; i16 < 2; ++i16)
#pragma unroll
      for (int j16 = 0; j16 < 4; ++j16)
#pragma unroll
        for (int r = 0; r < 4; ++r)
          macc[i16][j16][r] += exp2fast(sacc[i16][j16][r]) * li[i16][r];
    __syncthreads();
  }

  float* o = out1 + (size_t)b * 2048 * 2048;
#pragma unroll
  for (int i16 = 0; i16 < 2; ++i16)
#pragma unroll
    for (int j16 = 0; j16 < 4; ++j16)
#pragma unroll
      for (int r = 0; r < 4; ++r)
        o[(size_t)(i0 + w * 32 + i16 * 16 + quad * 4 + r) * 2048 + j0 + j16 * 16 + l16] =
            macc[i16][j16][r];
}

extern "C" void kernel_launch(void* const* d_in, const int* in_sizes, int n_in,
                              void* d_out, int out_size, void* d_ws, size_t ws_size,
                              hipStream_t stream) {
  (void)in_sizes; (void)n_in; (void)out_size; (void)ws_size;
  const float* query = (const float*)d_in[0];
  const float* key_  = (const float*)d_in[1];
  const float* value = (const float*)d_in[2];
  const float* Wq = (const float*)d_in[3];
  const float* bq = (const float*)d_in[4];
  const float* Wk = (const float*)d_in[5];
  const float* bk = (const float*)d_in[6];
  const float* Wv = (const float*)d_in[7];
  const float* bv = (const float*)d_in[8];
  const float* Wo = (const float*)d_in[9];
  const float* bo = (const float*)d_in[10];
  const float* Wf = (const float*)d_in[11];
  const float* bff = (const float*)d_in[12];
  const float* qw = (const float*)d_in[13];
  const float* entp = (const float*)d_in[14];

  char* p = (char*)d_ws;
  u16* Xq  = (u16*)(p + 0);
  u16* Xk  = (u16*)(p + 8388608);
  u16* Xv  = (u16*)(p + 16777216);
  u16* Wqb = (u16*)(p + 25165824);
  u16* Wkb = (u16*)(p + 27262976);
  u16* Wvb = (u16*)(p + 29360128);
  u16* Qp  = (u16*)(p + 33554432);
  u16* Kp  = (u16*)(p + 41943040);
  u16* VtG = (u16*)(p + 50331648);
  u16* Qaa = (u16*)(p + 58720256);
  u16* Kaa = (u16*)(p + 71303168);
  float* lb = (float*)(p + 84148224);
  u16* At  = (u16*)(p + 84410368);
  u16* Wob = (u16*)(p + 31457280);

  // 1) fused converts (dst = ws[0 .. 33.5MB) contiguous)
  k_f2b_all<<<16384, 256, 0, stream>>>(query, key_, value, Wq, Wk, Wv, Wo, Xq);

  // 2) fused QKV projections (z: 0=Q rm, 1=K rm, 2=V -> V^T)
  k_gemm128<<<dim3(8, 32, 3), 256, 0, stream>>>(Xq, Xk, Xv, Wqb, Wkb, Wvb, bq, bk, bv,
                                                Qp, Kp, VtG, nullptr);

  // 3) augmented feature rows (fused Q+K; K-side carries log2e)
  k_features<<<dim3(256, 2), 256, 0, stream>>>(Qp, Kp, Wf, bff, qw, entp, Qaa, Kaa);

  // 4) flash pass 1 (4-wave blocks, i-tile 64, deep prefetch)
  k_flash<<<dim3(32, 16, 2), 256, 0, stream>>>(Qaa, Kaa, VtG, At, lb);

  // 5) head-mean of attention probs
  k_pass2<<<dim3(32, 16, 2), 256, 0, stream>>>(Qaa, Kaa, lb, (float*)d_out + 4194304);

  // 6) output projection -> fp32 d_out[0:4194304]
  k_gemm128<<<dim3(8, 32, 1), 256, 0, stream>>>(At, At, At, Wob, Wob, Wob, bo, bo, bo,
                                                nullptr, nullptr, nullptr, (float*)d_out);
}

// Round 4
// 349.144 us; speedup vs baseline: 1.2313x; 1.2313x over previous
//
#include <hip/hip_runtime.h>

// QuantumAttentionMechanism on MI355X (gfx950)
// B=2, L=2048, D=1024, H=16, hd=64, Q=8.
//
// Algebra: combined score = ((1-ent)*Qh.Kh + ent^2*(w*cos qq).cos kq + ent^2*(w*sin qq).sin kq)/8
//          -> single 96-dim (80 used) bf16 GEMM over augmented Q~/K~ rows.
// R10: L3-BW diagnosis — R6/R8/R9 all sit at ~8-9 TB/s of K~/V streaming because the
//     default bid%8 XCD round-robin spreads all 32 (b,h) streams (20 MB) over every
//     4 MB XCD-L2. Fix: XCD-aware swizzles. k_flash = R6's exact proven structure
//     (4 waves x 32 rows, i-tile 128, reg-staged K dbuf depth-2, V 1-iter ahead,
//     [64][104] K tile) + 1D grid 512 with (bid&7)*64+bid/8 swizzle (4 (b,h)/XCD =
//     2.56 MB < L2) + exp2-direct + cvt_pk + setprio. k_pass2: XCD <- (b,i0-quad)
//     swizzle so co-resident i0-blocks reuse Ka tiles in L2.
// Workspace layout (bytes), total ~92.8 MB:
//   Xq 0  Xk 8388608  Xv 16777216 | Wqb 25165824 Wkb 27262976 Wvb 29360128 Wob 31457280
//   Qp 33554432 Kp 41943040 VtG 50331648 | Qa 58720256 Ka 71303168
//   (unused) 83886080 lbuf 84148224 | At 84410368  (end 92798976)

typedef unsigned short u16;
typedef unsigned int u32;
typedef short v8s __attribute__((ext_vector_type(8)));
typedef float v4f __attribute__((ext_vector_type(4)));

static __device__ __forceinline__ float b2f(u16 h) {
  union { u32 u; float f; } a; a.u = ((u32)h) << 16; return a.f;
}
static __device__ __forceinline__ u16 f2b(float f) {
  union { float f; u32 u; } a; a.f = f;
  u32 u = a.u;
  u32 r = u + 0x7FFFu + ((u >> 16) & 1u);  // RNE
  return (u16)(r >> 16);
}
static __device__ __forceinline__ v4f mfma16(v8s a, v8s b, v4f c) {
  return __builtin_amdgcn_mfma_f32_16x16x32_bf16(a, b, c, 0, 0, 0);
}
// async global->LDS, 16B per lane; LDS dest = wave-uniform base + lane*16
static __device__ __forceinline__ void gload16(const u16* g, u16* l) {
  __builtin_amdgcn_global_load_lds((const __attribute__((address_space(1))) u32*)g,
                                   (__attribute__((address_space(3))) u32*)l, 16, 0, 0);
}
// 2^x via the native transcendental (scores are pre-scaled by log2(e))
static __device__ __forceinline__ float exp2fast(float x) {
  float r; asm("v_exp_f32 %0, %1" : "=v"(r) : "v"(x)); return r;
}
// pack two f32 -> [bf16(hi)|bf16(lo)]
static __device__ __forceinline__ u32 cvtpk_bf16(float lo, float hi) {
  u32 r; asm("v_cvt_pk_bf16_f32 %0, %1, %2" : "=v"(r) : "v"(lo), "v"(hi)); return r;
}

// ---------------- fused fp32 -> bf16 convert (all 7 arrays; dst region contiguous) ----------
__global__ __launch_bounds__(256) void k_f2b_all(const float* __restrict__ q, const float* __restrict__ k,
                                                 const float* __restrict__ v, const float* __restrict__ wq,
                                                 const float* __restrict__ wk, const float* __restrict__ wv,
                                                 const float* __restrict__ wo, u16* __restrict__ y) {
  int i = blockIdx.x * 256 + threadIdx.x;  // group of 4 elems; 4194304 total
  const float* src; int off;
  if (i < 1048576)      { src = q;  off = i; }
  else if (i < 2097152) { src = k;  off = i - 1048576; }
  else if (i < 3145728) { src = v;  off = i - 2097152; }
  else if (i < 3407872) { src = wq; off = i - 3145728; }
  else if (i < 3670016) { src = wk; off = i - 3407872; }
  else if (i < 3932160) { src = wv; off = i - 3670016; }
  else                  { src = wo; off = i - 3932160; }
  float4 val = ((const float4*)src)[off];
  union { u16 s[4]; uint2 u; } o;
  o.s[0] = f2b(val.x); o.s[1] = f2b(val.y); o.s[2] = f2b(val.z); o.s[3] = f2b(val.w);
  ((uint2*)y)[i] = o.u;
}

// ---------------- 128x128xBK64 GEMM, C = A[M,K]*B[N,K]^T + bias (M=4096,N=K=1024) --------
// BK=64 stored as two 32-elem halves (each the m97 conflict-free unpadded layout).
// blockIdx.z selects operand set. Epilogue: Cf -> fp32 rm; z<2 -> bf16 rm; z==2 -> V^T via LDS.
__global__ __launch_bounds__(256) void k_gemm128(
    const u16* __restrict__ A0, const u16* __restrict__ A1, const u16* __restrict__ A2,
    const u16* __restrict__ B0, const u16* __restrict__ B1, const u16* __restrict__ B2,
    const float* __restrict__ bias0, const float* __restrict__ bias1, const float* __restrict__ bias2,
    u16* __restrict__ O0, u16* __restrict__ O1, u16* __restrict__ O2t,
    float* __restrict__ Cf) {
  __shared__ __align__(16) u16 pool[18432];  // 36.9 KB: As|Bs (32KB) / Ts (34.8KB) aliased
  u16* As = pool;             // [kk][row][32] : kk*4096 + row*32 + c
  u16* Bs = pool + 8192;
  const int K = 1024, N = 1024;
  int t = threadIdx.x, w = t >> 6, lane = t & 63, quad = lane >> 4, l16 = lane & 15;
  int z = blockIdx.z;
  const u16* A = (z == 0) ? A0 : (z == 1) ? A1 : A2;
  const u16* Bm = (z == 0) ? B0 : (z == 1) ? B1 : B2;
  const float* bias = (z == 0) ? bias0 : (z == 1) ? bias1 : bias2;
  int n0 = blockIdx.x * 128, m0 = blockIdx.y * 128;

  // staging: 8 instrs/wave; q: mat=q>>2, kk=(q>>1)&1, rowgroup g=w+(q&1)*4
  int srow = lane >> 2, scol = (lane & 3) * 8;
  const u16* gp[8]; u16* lp[8];
#pragma unroll
  for (int qi = 0; qi < 8; ++qi) {
    int mat = qi >> 2, kk = (qi >> 1) & 1, g = w + (qi & 1) * 4;
    int row = g * 16 + srow;
    gp[qi] = (mat ? Bm + (size_t)(n0 + row) * K : A + (size_t)(m0 + row) * K) + kk * 32 + scol;
    lp[qi] = (mat ? Bs : As) + kk * 4096 + g * 512;
  }

  int mrow = (w >> 1) * 64, ncol = (w & 1) * 64;
  v4f zf = {0.f, 0.f, 0.f, 0.f};
  v4f acc[4][4];
#pragma unroll
  for (int mi = 0; mi < 4; ++mi)
#pragma unroll
    for (int ni = 0; ni < 4; ++ni) acc[mi][ni] = zf;

  for (int k0 = 0; k0 < K; k0 += 64) {
    __syncthreads();
#pragma unroll
    for (int qi = 0; qi < 8; ++qi) gload16(gp[qi] + k0, lp[qi]);
    __syncthreads();  // drains vmcnt
#pragma unroll
    for (int kk = 0; kk < 2; ++kk) {
      v8s af[4], bfr[4];
#pragma unroll
      for (int x = 0; x < 4; ++x) {
        af[x] = *(const v8s*)&As[kk * 4096 + (mrow + x * 16 + l16) * 32 + quad * 8];
        bfr[x] = *(const v8s*)&Bs[kk * 4096 + (ncol + x * 16 + l16) * 32 + quad * 8];
      }
#pragma unroll
      for (int mi = 0; mi < 4; ++mi)
#pragma unroll
        for (int ni = 0; ni < 4; ++ni)
          acc[mi][ni] = mfma16(af[mi], bfr[ni], acc[mi][ni]);
    }
  }

  float bv[4];
#pragma unroll
  for (int ni = 0; ni < 4; ++ni) bv[ni] = bias[n0 + ncol + ni * 16 + l16];

  if (Cf) {
#pragma unroll
    for (int mi = 0; mi < 4; ++mi)
#pragma unroll
      for (int ni = 0; ni < 4; ++ni)
#pragma unroll
        for (int r = 0; r < 4; ++r)
          Cf[(size_t)(m0 + mrow + mi * 16 + quad * 4 + r) * N + n0 + ncol + ni * 16 + l16] =
              acc[mi][ni][r] + bv[ni];
  } else if (z != 2) {
    u16* O = z ? O1 : O0;
#pragma unroll
    for (int mi = 0; mi < 4; ++mi)
#pragma unroll
      for (int ni = 0; ni < 4; ++ni)
#pragma unroll
        for (int r = 0; r < 4; ++r)
          O[(size_t)(m0 + mrow + mi * 16 + quad * 4 + r) * N + n0 + ncol + ni * 16 + l16] =
              f2b(acc[mi][ni][r] + bv[ni]);
  } else {
    // V^T: reuse pool as Ts[w][64][68]; wave-local write/read (same-wave DS order)
    __syncthreads();  // everyone done with As/Bs
    u16* Ts = pool + w * 64 * 68;
#pragma unroll
    for (int mi = 0; mi < 4; ++mi)
#pragma unroll
      for (int ni = 0; ni < 4; ++ni)
#pragma unroll
        for (int r = 0; r < 4; ++r)
          Ts[(mi * 16 + quad * 4 + r) * 68 + ni * 16 + l16] = f2b(acc[mi][ni][r] + bv[ni]);
    int c = lane;
    union { uint4 u[8]; u16 s[64]; } cb;
#pragma unroll
    for (int e = 0; e < 64; ++e) cb.s[e] = Ts[e * 68 + c];
    int bb = m0 >> 11, ml = m0 & 2047;
    u16* dst = O2t + ((size_t)(bb * 1024 + n0 + ncol + c)) * 2048 + ml + mrow;
#pragma unroll
    for (int e = 0; e < 8; ++e) *(uint4*)(dst + e * 8) = cb.u[e];
  }
}

// ---------------- build augmented Q~/K~ rows [B,H,L,96]; fused Q+K via blockIdx.y --------
// K-side scale carries log2(e) so the flash/pass2 exponential is a single v_exp_f32.
__global__ __launch_bounds__(256) void k_features(const u16* __restrict__ Qp, const u16* __restrict__ Kp,
                                                  const float* __restrict__ Wf, const float* __restrict__ bff,
                                                  const float* __restrict__ qw, const float* __restrict__ entp,
                                                  u16* __restrict__ Qaa, u16* __restrict__ Kaa) {
  int isK = blockIdx.y;
  const u16* P = isK ? Kp : Qp;
  u16* Out = isK ? Kaa : Qaa;
  int idx = blockIdx.x * 256 + threadIdx.x;  // 0..65535 = b*H*L + h*L + l
  int b = idx >> 15, h = (idx >> 11) & 15, l = idx & 2047;
  const u16* src = P + ((size_t)(b * 2048 + l)) * 1024 + h * 64;
  u16* dst = Out + (size_t)idx * 96;
  const float4* Wf4 = (const float4*)Wf;

  float x[64];
#pragma unroll
  for (int g = 0; g < 8; ++g) {
    union { uint4 u; u16 s[8]; } uu;
    uu.u = *(const uint4*)(src + g * 8);
#pragma unroll
    for (int e = 0; e < 8; ++e) x[g * 8 + e] = b2f(uu.s[e]);
  }
  float qv[8];
#pragma unroll
  for (int qq = 0; qq < 8; ++qq) qv[qq] = bff[qq];
#pragma unroll
  for (int d = 0; d < 64; ++d) {
    float4 wa = Wf4[d * 2], wb = Wf4[d * 2 + 1];
    float xd = x[d];
    qv[0] += xd * wa.x; qv[1] += xd * wa.y; qv[2] += xd * wa.z; qv[3] += xd * wa.w;
    qv[4] += xd * wb.x; qv[5] += xd * wb.y; qv[6] += xd * wb.z; qv[7] += xd * wb.w;
  }
  float cs[8], sn[8];
#pragma unroll
  for (int qq = 0; qq < 8; ++qq) {
    float e2 = __expf(2.f * qv[qq]);
    float th = 1.f - 2.f / (e2 + 1.f);  // tanh
    __sincosf(th, &sn[qq], &cs[qq]);
  }
  float ent = 1.f / (1.f + __expf(-entp[0]));
  union { uint4 u; u16 s[8]; } pc, ps;
  if (!isK) {
#pragma unroll
    for (int g = 0; g < 8; ++g) *(uint4*)(dst + g * 8) = *(const uint4*)(src + g * 8);
#pragma unroll
    for (int qq = 0; qq < 8; ++qq) {
      float sw = 1.f / (1.f + __expf(-qw[h * 8 + qq]));
      pc.s[qq] = f2b(cs[qq] * sw);
      ps.s[qq] = f2b(sn[qq] * sw);
    }
  } else {
    const float LOG2E = 1.44269504088896f;
    float c1 = (1.f - ent) * 0.125f * LOG2E, c2 = ent * ent * 0.125f * LOG2E;
#pragma unroll
    for (int g = 0; g < 8; ++g) {
      union { uint4 u; u16 s[8]; } ob;
#pragma unroll
      for (int e = 0; e < 8; ++e) ob.s[e] = f2b(x[g * 8 + e] * c1);
      *(uint4*)(dst + g * 8) = ob.u;
    }
#pragma unroll
    for (int qq = 0; qq < 8; ++qq) {
      pc.s[qq] = f2b(cs[qq] * c2);
      ps.s[qq] = f2b(sn[qq] * c2);
    }
  }
  *(uint4*)(dst + 64) = pc.u;
  *(uint4*)(dst + 72) = ps.u;
  uint4 z4 = {0, 0, 0, 0};
  *(uint4*)(dst + 80) = z4;
  *(uint4*)(dst + 88) = z4;
}

// ---------------- flash pass 1 (S^T, no-max): R6 structure + XCD swizzle ----------
// 4 waves x 32 i-rows (i-tile 128), K reg-staged dbuf (depth-2 prefetch), V frags
// 1 iter ahead from global (L2-resident after swizzle), padded [64][104] K tile.
// 1D grid 512: sem=(bid&7)*64+bid/8 -> XCD x holds (b,h) in {x,x+8,x+16,x+24},
// all 16 i-blocks each -> per-XCD K~/V working set 2.56 MB < 4 MB L2.
__global__ __launch_bounds__(256) void k_flash(const u16* __restrict__ Qa, const u16* __restrict__ Ka,
                                               const u16* __restrict__ VtG, u16* __restrict__ At,
                                               float* __restrict__ lb) {
  __shared__ __align__(16) u16 Ks[2][64][104];   // double-buffered K~ tile [j][k]
  __shared__ __align__(16) u16 Ps[4][2][16][72]; // per-wave P [i16][i][j]

  int t = threadIdx.x, w = t >> 6, lane = t & 63, quad = lane >> 4, l16 = lane & 15;
  int bid = blockIdx.x;
  int sem = ((bid & 7) << 6) | (bid >> 3);  // XCD-contiguous semantic index
  int i0 = (sem & 15) << 7;                 // i-block (fastest within XCD -> L2 reuse)
  int hb = sem >> 4;                        // 0..31
  int h = hb & 15, b = hb >> 4;
  size_t qbase = ((size_t)(b * 16 + h)) * 2048 * 96;
  v8s aq[2][3];
#pragma unroll
  for (int i16 = 0; i16 < 2; ++i16) {
    const u16* Qrow = Qa + qbase + (size_t)(i0 + w * 32 + i16 * 16 + l16) * 96;
#pragma unroll
    for (int ks = 0; ks < 3; ++ks) aq[i16][ks] = *(const v8s*)(Qrow + ks * 32 + quad * 8);
  }
  const u16* Kbase = Ka + qbase;
  const u16* Vbase = VtG + ((size_t)(b * 1024 + h * 64)) * 2048;

  // K staging: 64x96 = 768 16B-groups, 3/thread
  const u16* kg[3]; int kdo[3];
#pragma unroll
  for (int p = 0; p < 3; ++p) {
    int idx = t + p * 256, r_ = idx / 12, c_ = idx % 12;
    kg[p] = Kbase + (size_t)r_ * 96 + c_ * 8;
    kdo[p] = r_ * 104 + c_ * 8;
  }
  u16* ks0 = &Ks[0][0][0];
  u16* ks1 = &Ks[1][0][0];

  v4f zf = {0.f, 0.f, 0.f, 0.f};
  v4f oacc[2][4];
#pragma unroll
  for (int i16 = 0; i16 < 2; ++i16)
#pragma unroll
    for (int d16 = 0; d16 < 4; ++d16) oacc[i16][d16] = zf;
  float l_acc[2] = {0.f, 0.f};

  // prologue: stage j=0 into buf0; regs hold j=64; V frags for j=0
  uint4 fk0 = *(const uint4*)kg[0];
  uint4 fk1 = *(const uint4*)kg[1];
  uint4 fk2 = *(const uint4*)kg[2];
  kg[0] += 6144; kg[1] += 6144; kg[2] += 6144;
  *(uint4*)(ks0 + kdo[0]) = fk0;
  *(uint4*)(ks0 + kdo[1]) = fk1;
  *(uint4*)(ks0 + kdo[2]) = fk2;
  fk0 = *(const uint4*)kg[0];
  fk1 = *(const uint4*)kg[1];
  fk2 = *(const uint4*)kg[2];
  kg[0] += 6144; kg[1] += 6144; kg[2] += 6144;
  v8s vf[8];
#pragma unroll
  for (int idx = 0; idx < 8; ++idx)
    vf[idx] = *(const v8s*)(Vbase + (size_t)((idx >> 1) * 16 + l16) * 2048 + (idx & 1) * 32 + quad * 8);
  __syncthreads();

  for (int j0 = 0; j0 < 2048; j0 += 64) {
    int cur = (j0 >> 6) & 1;
    const u16* kb = cur ? ks1 : ks0;
    u16* kw = cur ? ks0 : ks1;
    bool more = (j0 + 64) < 2048;
    if (more) {  // write next tile (regs) into alternate buffer
      *(uint4*)(kw + kdo[0]) = fk0;
      *(uint4*)(kw + kdo[1]) = fk1;
      *(uint4*)(kw + kdo[2]) = fk2;
    }
    if (j0 + 128 < 2048) {  // prefetch next-next K tile
      fk0 = *(const uint4*)kg[0];
      fk1 = *(const uint4*)kg[1];
      fk2 = *(const uint4*)kg[2];
      kg[0] += 6144; kg[1] += 6144; kg[2] += 6144;
    }
    v8s vn[8];
    if (more) {  // prefetch next V frags (L2)
#pragma unroll
      for (int idx = 0; idx < 8; ++idx)
        vn[idx] = *(const v8s*)(Vbase + (size_t)((idx >> 1) * 16 + l16) * 2048 + j0 + 64 +
                                (idx & 1) * 32 + quad * 8);
    }

    // S^T: sacc[i16][j16] row=j(quad*4+r), col=i(l16)
    v4f sacc[2][4];
#pragma unroll
    for (int i16 = 0; i16 < 2; ++i16)
#pragma unroll
      for (int j16 = 0; j16 < 4; ++j16) sacc[i16][j16] = zf;
    __builtin_amdgcn_s_setprio(1);
#pragma unroll
    for (int j16 = 0; j16 < 4; ++j16)
#pragma unroll
      for (int ks = 0; ks < 3; ++ks) {
        v8s kf = *(const v8s*)(kb + (j16 * 16 + l16) * 104 + ks * 32 + quad * 8);
        sacc[0][j16] = mfma16(kf, aq[0][ks], sacc[0][j16]);
        sacc[1][j16] = mfma16(kf, aq[1][ks], sacc[1][j16]);
      }
    __builtin_amdgcn_s_setprio(0);

    // exp2 (scores pre-scaled by log2e) + row-sum + pack via cvt_pk
#pragma unroll
    for (int i16 = 0; i16 < 2; ++i16)
#pragma unroll
      for (int j16 = 0; j16 < 4; ++j16) {
        float e0 = exp2fast(sacc[i16][j16][0]);
        float e1 = exp2fast(sacc[i16][j16][1]);
        float e2 = exp2fast(sacc[i16][j16][2]);
        float e3 = exp2fast(sacc[i16][j16][3]);
        l_acc[i16] += (e0 + e1) + (e2 + e3);
        uint2 pp;
        pp.x = cvtpk_bf16(e0, e1);
        pp.y = cvtpk_bf16(e2, e3);
        *(uint2*)&Ps[w][i16][l16][j16 * 16 + quad * 4] = pp;
      }

    // PV: P from per-wave LDS (same-wave DS order), V from registers
    __builtin_amdgcn_s_setprio(1);
#pragma unroll
    for (int jh = 0; jh < 2; ++jh) {
      v8s pf0 = *(const v8s*)&Ps[w][0][l16][jh * 32 + quad * 8];
      v8s pf1 = *(const v8s*)&Ps[w][1][l16][jh * 32 + quad * 8];
#pragma unroll
      for (int d16 = 0; d16 < 4; ++d16) {
        v8s vv = vf[d16 * 2 + jh];
        oacc[0][d16] = mfma16(pf0, vv, oacc[0][d16]);
        oacc[1][d16] = mfma16(pf1, vv, oacc[1][d16]);
      }
    }
    __builtin_amdgcn_s_setprio(0);
    if (more) {
#pragma unroll
      for (int idx = 0; idx < 8; ++idx) vf[idx] = vn[idx];
      __syncthreads();
    }
  }

#pragma unroll
  for (int i16 = 0; i16 < 2; ++i16) {
    l_acc[i16] += __shfl_xor(l_acc[i16], 16, 64);
    l_acc[i16] += __shfl_xor(l_acc[i16], 32, 64);
    float linv = 1.f / l_acc[i16];
#pragma unroll
    for (int r = 0; r < 4; ++r) {
      float li = __shfl(linv, quad * 4 + r, 64);
      int ri = i0 + w * 32 + i16 * 16 + quad * 4 + r;
#pragma unroll
      for (int d16 = 0; d16 < 4; ++d16)
        At[((size_t)(b * 2048 + ri)) * 1024 + h * 64 + d16 * 16 + l16] = f2b(oacc[i16][d16][r] * li);
    }
    if (lane < 16) {
      size_t mbase = ((size_t)(b * 16 + h)) * 2048;
      lb[mbase + i0 + w * 32 + i16 * 16 + lane] = l_acc[i16];
    }
  }
}

// ---------------- pass 2: attn.mean over heads -> out1[B,L,L]; XCD-swizzled ----------------
// 1D grid 1024. XCD <- (b, i0-quad): per-XCD Qa slice 1.57 MB resident; the 4
// co-resident i0-blocks per j0 share each Ka tile -> Ka read ~once per XCD.
__global__ __launch_bounds__(256) void k_pass2(const u16* __restrict__ Qa, const u16* __restrict__ Ka,
                                               const float* __restrict__ lb,
                                               float* __restrict__ out1) {
  __shared__ __align__(16) u16 Ks[64][104];
  __shared__ float Ls[16][128];
  int t = threadIdx.x, w = t >> 6, lane = t & 63, quad = lane >> 4, l16 = lane & 15;
  int bid = blockIdx.x;
  int sem = ((bid & 7) << 7) | (bid >> 3);
  int xcd = sem >> 7;                                   // 0..7
  int b = xcd >> 2;                                     // 0..1
  int i0 = ((((xcd & 3) << 2) | (sem & 3))) << 7;       // 16 i-blocks * 128
  int j0 = ((sem >> 2) & 31) << 6;                      // 32 j-blocks * 64

#pragma unroll
  for (int rep = 0; rep < 8; ++rep) {
    int idx = t + rep * 256;
    int hh = idx >> 7, il = idx & 127;
    Ls[hh][il] = 0.0625f / lb[((size_t)(b * 16 + hh)) * 2048 + i0 + il];
  }

  size_t base0 = (size_t)b * 16 * 2048 * 96;
  const u16* kg[3]; u16* kd[3];
#pragma unroll
  for (int rep = 0; rep < 3; ++rep) {
    int idx = t + rep * 256;
    int r_ = idx / 12, c_ = idx % 12;
    kg[rep] = Ka + base0 + (size_t)(j0 + r_) * 96 + c_ * 8;
    kd[rep] = &Ks[r_][c_ * 8];
  }
  uint4 f0 = *(const uint4*)kg[0];
  uint4 f1 = *(const uint4*)kg[1];
  uint4 f2 = *(const uint4*)kg[2];

  const u16* q0 = Qa + base0 + (size_t)(i0 + w * 32 + l16) * 96 + quad * 8;
  const u16* q1 = q0 + 16 * 96;

  v4f zf = {0.f, 0.f, 0.f, 0.f};
  v4f macc[2][4];
#pragma unroll
  for (int i16 = 0; i16 < 2; ++i16)
#pragma unroll
    for (int j16 = 0; j16 < 4; ++j16) macc[i16][j16] = zf;

  v8s a[2][3];
#pragma unroll
  for (int ks = 0; ks < 3; ++ks) {
    a[0][ks] = *(const v8s*)(q0 + ks * 32);
    a[1][ks] = *(const v8s*)(q1 + ks * 32);
  }

  for (int h = 0; h < 16; ++h) {
    *(uint4*)kd[0] = f0;
    *(uint4*)kd[1] = f1;
    *(uint4*)kd[2] = f2;
    __syncthreads();
    if (h < 15) {
      kg[0] += 196608; kg[1] += 196608; kg[2] += 196608;
      f0 = *(const uint4*)kg[0];
      f1 = *(const uint4*)kg[1];
      f2 = *(const uint4*)kg[2];
    }

    v4f sacc[2][4];
#pragma unroll
    for (int i16 = 0; i16 < 2; ++i16)
#pragma unroll
      for (int j16 = 0; j16 < 4; ++j16) sacc[i16][j16] = zf;
#pragma unroll
    for (int ks = 0; ks < 3; ++ks)
#pragma unroll
      for (int j16 = 0; j16 < 4; ++j16) {
        v8s kf = *(const v8s*)&Ks[j16 * 16 + l16][ks * 32 + quad * 8];
        sacc[0][j16] = mfma16(a[0][ks], kf, sacc[0][j16]);
        sacc[1][j16] = mfma16(a[1][ks], kf, sacc[1][j16]);
      }

    if (h < 15) {
      q0 += 196608; q1 += 196608;
#pragma unroll
      for (int ks = 0; ks < 3; ++ks) {
        a[0][ks] = *(const v8s*)(q0 + ks * 32);
        a[1][ks] = *(const v8s*)(q1 + ks * 32);
      }
    }

    float li[2][4];
#pragma unroll
    for (int i16 = 0; i16 < 2; ++i16)
#pragma unroll
      for (int r = 0; r < 4; ++r)
        li[i16][r] = Ls[h][w * 32 + i16 * 16 + quad * 4 + r];
#pragma unroll
    for (int i16 = 0; i16 < 2; ++i16)
#pragma unroll
      for (int j16 = 0; j16 < 4; ++j16)
#pragma unroll
        for (int r = 0; r < 4; ++r)
          macc[i16][j16][r] += exp2fast(sacc[i16][j16][r]) * li[i16][r];
    __syncthreads();
  }

  float* o = out1 + (size_t)b * 2048 * 2048;
#pragma unroll
  for (int i16 = 0; i16 < 2; ++i16)
#pragma unroll
    for (int j16 = 0; j16 < 4; ++j16)
#pragma unroll
      for (int r = 0; r < 4; ++r)
        o[(size_t)(i0 + w * 32 + i16 * 16 + quad * 4 + r) * 2048 + j0 + j16 * 16 + l16] =
            macc[i16][j16][r];
}

extern "C" void kernel_launch(void* const* d_in, const int* in_sizes, int n_in,
                              void* d_out, int out_size, void* d_ws, size_t ws_size,
                              hipStream_t stream) {
  (void)in_sizes; (void)n_in; (void)out_size; (void)ws_size;
  const float* query = (const float*)d_in[0];
  const float* key_  = (const float*)d_in[1];
  const float* value = (const float*)d_in[2];
  const float* Wq = (const float*)d_in[3];
  const float* bq = (const float*)d_in[4];
  const float* Wk = (const float*)d_in[5];
  const float* bk = (const float*)d_in[6];
  const float* Wv = (const float*)d_in[7];
  const float* bv = (const float*)d_in[8];
  const float* Wo = (const float*)d_in[9];
  const float* bo = (const float*)d_in[10];
  const float* Wf = (const float*)d_in[11];
  const float* bff = (const float*)d_in[12];
  const float* qw = (const float*)d_in[13];
  const float* entp = (const float*)d_in[14];

  char* p = (char*)d_ws;
  u16* Xq  = (u16*)(p + 0);
  u16* Xk  = (u16*)(p + 8388608);
  u16* Xv  = (u16*)(p + 16777216);
  u16* Wqb = (u16*)(p + 25165824);
  u16* Wkb = (u16*)(p + 27262976);
  u16* Wvb = (u16*)(p + 29360128);
  u16* Qp  = (u16*)(p + 33554432);
  u16* Kp  = (u16*)(p + 41943040);
  u16* VtG = (u16*)(p + 50331648);
  u16* Qaa = (u16*)(p + 58720256);
  u16* Kaa = (u16*)(p + 71303168);
  float* lb = (float*)(p + 84148224);
  u16* At  = (u16*)(p + 84410368);
  u16* Wob = (u16*)(p + 31457280);

  // 1) fused converts (dst = ws[0 .. 33.5MB) contiguous)
  k_f2b_all<<<16384, 256, 0, stream>>>(query, key_, value, Wq, Wk, Wv, Wo, Xq);

  // 2) fused QKV projections (z: 0=Q rm, 1=K rm, 2=V -> V^T)
  k_gemm128<<<dim3(8, 32, 3), 256, 0, stream>>>(Xq, Xk, Xv, Wqb, Wkb, Wvb, bq, bk, bv,
                                                Qp, Kp, VtG, nullptr);

  // 3) augmented feature rows (fused Q+K; K-side carries log2e)
  k_features<<<dim3(256, 2), 256, 0, stream>>>(Qp, Kp, Wf, bff, qw, entp, Qaa, Kaa);

  // 4) flash pass 1 (R6 structure, XCD-swizzled 1D grid)
  k_flash<<<dim3(512), 256, 0, stream>>>(Qaa, Kaa, VtG, At, lb);

  // 5) head-mean of attention probs (XCD-swizzled 1D grid)
  k_pass2<<<dim3(1024), 256, 0, stream>>>(Qaa, Kaa, lb, (float*)d_out + 4194304);

  // 6) output projection -> fp32 d_out[0:4194304]
  k_gemm128<<<dim3(8, 32, 1), 256, 0, stream>>>(At, At, At, Wob, Wob, Wob, bo, bo, bo,
                                                nullptr, nullptr, nullptr, (float*)d_out);
}

// Round 5
// 330.811 us; speedup vs baseline: 1.2995x; 1.0554x over previous
//
#include <hip/hip_runtime.h>

// QuantumAttentionMechanism on MI355X (gfx950)
// B=2, L=2048, D=1024, H=16, hd=64, Q=8.
//
// Algebra: combined score = ((1-ent)*Qh.Kh + ent^2*(w*cos qq).cos kq + ent^2*(w*sin qq).sin kq)/8
//          -> single 96-dim (80 used) bf16 GEMM over augmented Q~/K~ rows.
// R11: per-CU shared-pipe theory (R6/R9/R10 invariant ~6900cyc/iter; FETCH fix in R10
//     changed nothing -> not BW-bound). Cut VMEM scatter 4x: V staged into LDS once
//     per block ([2][64][72] pad, 16B-aligned rows, ~2-way reads), prefetch 1 iter
//     ahead, 8 near-contiguous stage loads replace 32 redundant 16-segment gathers.
//     Frees 64 VGPR. K path / Ps path / exp2 / cvtpk / setprio / XCD swizzle = R10.
// Workspace layout (bytes), total ~92.8 MB:
//   Xq 0  Xk 8388608  Xv 16777216 | Wqb 25165824 Wkb 27262976 Wvb 29360128 Wob 31457280
//   Qp 33554432 Kp 41943040 VtG 50331648 | Qa 58720256 Ka 71303168
//   (unused) 83886080 lbuf 84148224 | At 84410368  (end 92798976)

typedef unsigned short u16;
typedef unsigned int u32;
typedef short v8s __attribute__((ext_vector_type(8)));
typedef float v4f __attribute__((ext_vector_type(4)));

static __device__ __forceinline__ float b2f(u16 h) {
  union { u32 u; float f; } a; a.u = ((u32)h) << 16; return a.f;
}
static __device__ __forceinline__ u16 f2b(float f) {
  union { float f; u32 u; } a; a.f = f;
  u32 u = a.u;
  u32 r = u + 0x7FFFu + ((u >> 16) & 1u);  // RNE
  return (u16)(r >> 16);
}
static __device__ __forceinline__ v4f mfma16(v8s a, v8s b, v4f c) {
  return __builtin_amdgcn_mfma_f32_16x16x32_bf16(a, b, c, 0, 0, 0);
}
// async global->LDS, 16B per lane; LDS dest = wave-uniform base + lane*16
static __device__ __forceinline__ void gload16(const u16* g, u16* l) {
  __builtin_amdgcn_global_load_lds((const __attribute__((address_space(1))) u32*)g,
                                   (__attribute__((address_space(3))) u32*)l, 16, 0, 0);
}
// 2^x via the native transcendental (scores are pre-scaled by log2(e))
static __device__ __forceinline__ float exp2fast(float x) {
  float r; asm("v_exp_f32 %0, %1" : "=v"(r) : "v"(x)); return r;
}
// pack two f32 -> [bf16(hi)|bf16(lo)]
static __device__ __forceinline__ u32 cvtpk_bf16(float lo, float hi) {
  u32 r; asm("v_cvt_pk_bf16_f32 %0, %1, %2" : "=v"(r) : "v"(lo), "v"(hi)); return r;
}

// ---------------- fused fp32 -> bf16 convert (all 7 arrays; dst region contiguous) ----------
__global__ __launch_bounds__(256) void k_f2b_all(const float* __restrict__ q, const float* __restrict__ k,
                                                 const float* __restrict__ v, const float* __restrict__ wq,
                                                 const float* __restrict__ wk, const float* __restrict__ wv,
                                                 const float* __restrict__ wo, u16* __restrict__ y) {
  int i = blockIdx.x * 256 + threadIdx.x;  // group of 4 elems; 4194304 total
  const float* src; int off;
  if (i < 1048576)      { src = q;  off = i; }
  else if (i < 2097152) { src = k;  off = i - 1048576; }
  else if (i < 3145728) { src = v;  off = i - 2097152; }
  else if (i < 3407872) { src = wq; off = i - 3145728; }
  else if (i < 3670016) { src = wk; off = i - 3407872; }
  else if (i < 3932160) { src = wv; off = i - 3670016; }
  else                  { src = wo; off = i - 3932160; }
  float4 val = ((const float4*)src)[off];
  union { u16 s[4]; uint2 u; } o;
  o.s[0] = f2b(val.x); o.s[1] = f2b(val.y); o.s[2] = f2b(val.z); o.s[3] = f2b(val.w);
  ((uint2*)y)[i] = o.u;
}

// ---------------- 128x128xBK64 GEMM, C = A[M,K]*B[N,K]^T + bias (M=4096,N=K=1024) --------
// BK=64 stored as two 32-elem halves (each the m97 conflict-free unpadded layout).
// blockIdx.z selects operand set. Epilogue: Cf -> fp32 rm; z<2 -> bf16 rm; z==2 -> V^T via LDS.
__global__ __launch_bounds__(256) void k_gemm128(
    const u16* __restrict__ A0, const u16* __restrict__ A1, const u16* __restrict__ A2,
    const u16* __restrict__ B0, const u16* __restrict__ B1, const u16* __restrict__ B2,
    const float* __restrict__ bias0, const float* __restrict__ bias1, const float* __restrict__ bias2,
    u16* __restrict__ O0, u16* __restrict__ O1, u16* __restrict__ O2t,
    float* __restrict__ Cf) {
  __shared__ __align__(16) u16 pool[18432];  // 36.9 KB: As|Bs (32KB) / Ts (34.8KB) aliased
  u16* As = pool;             // [kk][row][32] : kk*4096 + row*32 + c
  u16* Bs = pool + 8192;
  const int K = 1024, N = 1024;
  int t = threadIdx.x, w = t >> 6, lane = t & 63, quad = lane >> 4, l16 = lane & 15;
  int z = blockIdx.z;
  const u16* A = (z == 0) ? A0 : (z == 1) ? A1 : A2;
  const u16* Bm = (z == 0) ? B0 : (z == 1) ? B1 : B2;
  const float* bias = (z == 0) ? bias0 : (z == 1) ? bias1 : bias2;
  int n0 = blockIdx.x * 128, m0 = blockIdx.y * 128;

  // staging: 8 instrs/wave; q: mat=q>>2, kk=(q>>1)&1, rowgroup g=w+(q&1)*4
  int srow = lane >> 2, scol = (lane & 3) * 8;
  const u16* gp[8]; u16* lp[8];
#pragma unroll
  for (int qi = 0; qi < 8; ++qi) {
    int mat = qi >> 2, kk = (qi >> 1) & 1, g = w + (qi & 1) * 4;
    int row = g * 16 + srow;
    gp[qi] = (mat ? Bm + (size_t)(n0 + row) * K : A + (size_t)(m0 + row) * K) + kk * 32 + scol;
    lp[qi] = (mat ? Bs : As) + kk * 4096 + g * 512;
  }

  int mrow = (w >> 1) * 64, ncol = (w & 1) * 64;
  v4f zf = {0.f, 0.f, 0.f, 0.f};
  v4f acc[4][4];
#pragma unroll
  for (int mi = 0; mi < 4; ++mi)
#pragma unroll
    for (int ni = 0; ni < 4; ++ni) acc[mi][ni] = zf;

  for (int k0 = 0; k0 < K; k0 += 64) {
    __syncthreads();
#pragma unroll
    for (int qi = 0; qi < 8; ++qi) gload16(gp[qi] + k0, lp[qi]);
    __syncthreads();  // drains vmcnt
#pragma unroll
    for (int kk = 0; kk < 2; ++kk) {
      v8s af[4], bfr[4];
#pragma unroll
      for (int x = 0; x < 4; ++x) {
        af[x] = *(const v8s*)&As[kk * 4096 + (mrow + x * 16 + l16) * 32 + quad * 8];
        bfr[x] = *(const v8s*)&Bs[kk * 4096 + (ncol + x * 16 + l16) * 32 + quad * 8];
      }
#pragma unroll
      for (int mi = 0; mi < 4; ++mi)
#pragma unroll
        for (int ni = 0; ni < 4; ++ni)
          acc[mi][ni] = mfma16(af[mi], bfr[ni], acc[mi][ni]);
    }
  }

  float bv[4];
#pragma unroll
  for (int ni = 0; ni < 4; ++ni) bv[ni] = bias[n0 + ncol + ni * 16 + l16];

  if (Cf) {
#pragma unroll
    for (int mi = 0; mi < 4; ++mi)
#pragma unroll
      for (int ni = 0; ni < 4; ++ni)
#pragma unroll
        for (int r = 0; r < 4; ++r)
          Cf[(size_t)(m0 + mrow + mi * 16 + quad * 4 + r) * N + n0 + ncol + ni * 16 + l16] =
              acc[mi][ni][r] + bv[ni];
  } else if (z != 2) {
    u16* O = z ? O1 : O0;
#pragma unroll
    for (int mi = 0; mi < 4; ++mi)
#pragma unroll
      for (int ni = 0; ni < 4; ++ni)
#pragma unroll
        for (int r = 0; r < 4; ++r)
          O[(size_t)(m0 + mrow + mi * 16 + quad * 4 + r) * N + n0 + ncol + ni * 16 + l16] =
              f2b(acc[mi][ni][r] + bv[ni]);
  } else {
    // V^T: reuse pool as Ts[w][64][68]; wave-local write/read (same-wave DS order)
    __syncthreads();  // everyone done with As/Bs
    u16* Ts = pool + w * 64 * 68;
#pragma unroll
    for (int mi = 0; mi < 4; ++mi)
#pragma unroll
      for (int ni = 0; ni < 4; ++ni)
#pragma unroll
        for (int r = 0; r < 4; ++r)
          Ts[(mi * 16 + quad * 4 + r) * 68 + ni * 16 + l16] = f2b(acc[mi][ni][r] + bv[ni]);
    int c = lane;
    union { uint4 u[8]; u16 s[64]; } cb;
#pragma unroll
    for (int e = 0; e < 64; ++e) cb.s[e] = Ts[e * 68 + c];
    int bb = m0 >> 11, ml = m0 & 2047;
    u16* dst = O2t + ((size_t)(bb * 1024 + n0 + ncol + c)) * 2048 + ml + mrow;
#pragma unroll
    for (int e = 0; e < 8; ++e) *(uint4*)(dst + e * 8) = cb.u[e];
  }
}

// ---------------- build augmented Q~/K~ rows [B,H,L,96]; fused Q+K via blockIdx.y --------
// K-side scale carries log2(e) so the flash/pass2 exponential is a single v_exp_f32.
__global__ __launch_bounds__(256) void k_features(const u16* __restrict__ Qp, const u16* __restrict__ Kp,
                                                  const float* __restrict__ Wf, const float* __restrict__ bff,
                                                  const float* __restrict__ qw, const float* __restrict__ entp,
                                                  u16* __restrict__ Qaa, u16* __restrict__ Kaa) {
  int isK = blockIdx.y;
  const u16* P = isK ? Kp : Qp;
  u16* Out = isK ? Kaa : Qaa;
  int idx = blockIdx.x * 256 + threadIdx.x;  // 0..65535 = b*H*L + h*L + l
  int b = idx >> 15, h = (idx >> 11) & 15, l = idx & 2047;
  const u16* src = P + ((size_t)(b * 2048 + l)) * 1024 + h * 64;
  u16* dst = Out + (size_t)idx * 96;
  const float4* Wf4 = (const float4*)Wf;

  float x[64];
#pragma unroll
  for (int g = 0; g < 8; ++g) {
    union { uint4 u; u16 s[8]; } uu;
    uu.u = *(const uint4*)(src + g * 8);
#pragma unroll
    for (int e = 0; e < 8; ++e) x[g * 8 + e] = b2f(uu.s[e]);
  }
  float qv[8];
#pragma unroll
  for (int qq = 0; qq < 8; ++qq) qv[qq] = bff[qq];
#pragma unroll
  for (int d = 0; d < 64; ++d) {
    float4 wa = Wf4[d * 2], wb = Wf4[d * 2 + 1];
    float xd = x[d];
    qv[0] += xd * wa.x; qv[1] += xd * wa.y; qv[2] += xd * wa.z; qv[3] += xd * wa.w;
    qv[4] += xd * wb.x; qv[5] += xd * wb.y; qv[6] += xd * wb.z; qv[7] += xd * wb.w;
  }
  float cs[8], sn[8];
#pragma unroll
  for (int qq = 0; qq < 8; ++qq) {
    float e2 = __expf(2.f * qv[qq]);
    float th = 1.f - 2.f / (e2 + 1.f);  // tanh
    __sincosf(th, &sn[qq], &cs[qq]);
  }
  float ent = 1.f / (1.f + __expf(-entp[0]));
  union { uint4 u; u16 s[8]; } pc, ps;
  if (!isK) {
#pragma unroll
    for (int g = 0; g < 8; ++g) *(uint4*)(dst + g * 8) = *(const uint4*)(src + g * 8);
#pragma unroll
    for (int qq = 0; qq < 8; ++qq) {
      float sw = 1.f / (1.f + __expf(-qw[h * 8 + qq]));
      pc.s[qq] = f2b(cs[qq] * sw);
      ps.s[qq] = f2b(sn[qq] * sw);
    }
  } else {
    const float LOG2E = 1.44269504088896f;
    float c1 = (1.f - ent) * 0.125f * LOG2E, c2 = ent * ent * 0.125f * LOG2E;
#pragma unroll
    for (int g = 0; g < 8; ++g) {
      union { uint4 u; u16 s[8]; } ob;
#pragma unroll
      for (int e = 0; e < 8; ++e) ob.s[e] = f2b(x[g * 8 + e] * c1);
      *(uint4*)(dst + g * 8) = ob.u;
    }
#pragma unroll
    for (int qq = 0; qq < 8; ++qq) {
      pc.s[qq] = f2b(cs[qq] * c2);
      ps.s[qq] = f2b(sn[qq] * c2);
    }
  }
  *(uint4*)(dst + 64) = pc.u;
  *(uint4*)(dst + 72) = ps.u;
  uint4 z4 = {0, 0, 0, 0};
  *(uint4*)(dst + 80) = z4;
  *(uint4*)(dst + 88) = z4;
}

// ---------------- flash pass 1 (S^T, no-max): R10 structure + V-in-LDS ----------
// 4 waves x 32 i-rows (i-tile 128), K reg-staged dbuf (depth-2 prefetch), V staged
// cooperatively into LDS dbuf [2][64][72] (1 iter ahead; 8 near-contiguous stage
// loads/block-iter replace 32 redundant 16-segment gathers). XCD-swizzled 1D grid.
__global__ __launch_bounds__(256) void k_flash(const u16* __restrict__ Qa, const u16* __restrict__ Ka,
                                               const u16* __restrict__ VtG, u16* __restrict__ At,
                                               float* __restrict__ lb) {
  __shared__ __align__(16) u16 Ks[2][64][104];   // double-buffered K~ tile [j][k]
  __shared__ __align__(16) u16 Vs[2][64][72];    // double-buffered V^T tile [d][j], 16B rows
  __shared__ __align__(16) u16 Ps[4][2][16][72]; // per-wave P [i16][i][j]

  int t = threadIdx.x, w = t >> 6, lane = t & 63, quad = lane >> 4, l16 = lane & 15;
  int bid = blockIdx.x;
  int sem = ((bid & 7) << 6) | (bid >> 3);  // XCD-contiguous semantic index
  int i0 = (sem & 15) << 7;                 // i-block (fastest within XCD -> L2 reuse)
  int hb = sem >> 4;                        // 0..31
  int h = hb & 15, b = hb >> 4;
  size_t qbase = ((size_t)(b * 16 + h)) * 2048 * 96;
  v8s aq[2][3];
#pragma unroll
  for (int i16 = 0; i16 < 2; ++i16) {
    const u16* Qrow = Qa + qbase + (size_t)(i0 + w * 32 + i16 * 16 + l16) * 96;
#pragma unroll
    for (int ks = 0; ks < 3; ++ks) aq[i16][ks] = *(const v8s*)(Qrow + ks * 32 + quad * 8);
  }
  const u16* Kbase = Ka + qbase;
  const u16* Vbase = VtG + ((size_t)(b * 1024 + h * 64)) * 2048;

  // K staging: 64x96 = 768 16B-groups, 3/thread
  const u16* kg[3]; int kdo[3];
#pragma unroll
  for (int p = 0; p < 3; ++p) {
    int idx = t + p * 256, r_ = idx / 12, c_ = idx % 12;
    kg[p] = Kbase + (size_t)r_ * 96 + c_ * 8;
    kdo[p] = r_ * 104 + c_ * 8;
  }
  u16* ks0 = &Ks[0][0][0];
  u16* ks1 = &Ks[1][0][0];

  // V staging: 64 rows x 64 cols = 512 16B-chunks, 2/thread (rows t>>3 and t>>3+32)
  const u16* vg0 = Vbase + (size_t)(t >> 3) * 2048 + (t & 7) * 8;
  const u16* vg1 = vg0 + (size_t)32 * 2048;
  u16* vsb = &Vs[0][0][0];
  int vdo0 = (t >> 3) * 72 + (t & 7) * 8;
  int vdo1 = vdo0 + 32 * 72;
  const int VSTRIDE = 64 * 72;  // u16 per V buffer

  v4f zf = {0.f, 0.f, 0.f, 0.f};
  v4f oacc[2][4];
#pragma unroll
  for (int i16 = 0; i16 < 2; ++i16)
#pragma unroll
    for (int d16 = 0; d16 < 4; ++d16) oacc[i16][d16] = zf;
  float l_acc[2] = {0.f, 0.f};

  // prologue: stage K j=0 into buf0; K j=64 in regs; V j=0 into buf0
  uint4 fk0 = *(const uint4*)kg[0];
  uint4 fk1 = *(const uint4*)kg[1];
  uint4 fk2 = *(const uint4*)kg[2];
  kg[0] += 6144; kg[1] += 6144; kg[2] += 6144;
  *(uint4*)(ks0 + kdo[0]) = fk0;
  *(uint4*)(ks0 + kdo[1]) = fk1;
  *(uint4*)(ks0 + kdo[2]) = fk2;
  fk0 = *(const uint4*)kg[0];
  fk1 = *(const uint4*)kg[1];
  fk2 = *(const uint4*)kg[2];
  kg[0] += 6144; kg[1] += 6144; kg[2] += 6144;
  uint4 va0 = *(const uint4*)vg0;
  uint4 va1 = *(const uint4*)vg1;
  *(uint4*)(vsb + vdo0) = va0;
  *(uint4*)(vsb + vdo1) = va1;
  __syncthreads();

  for (int j0 = 0; j0 < 2048; j0 += 64) {
    int cur = (j0 >> 6) & 1;
    const u16* kb = cur ? ks1 : ks0;
    u16* kw = cur ? ks0 : ks1;
    const u16* vcur = vsb + cur * VSTRIDE;
    bool more = (j0 + 64) < 2048;
    if (more) {  // write next K tile (regs) into alternate buffer
      *(uint4*)(kw + kdo[0]) = fk0;
      *(uint4*)(kw + kdo[1]) = fk1;
      *(uint4*)(kw + kdo[2]) = fk2;
    }
    if (j0 + 128 < 2048) {  // prefetch next-next K tile
      fk0 = *(const uint4*)kg[0];
      fk1 = *(const uint4*)kg[1];
      fk2 = *(const uint4*)kg[2];
      kg[0] += 6144; kg[1] += 6144; kg[2] += 6144;
    }
    if (more) {  // issue next V tile loads (land during this iter's compute)
      va0 = *(const uint4*)(vg0 + j0 + 64);
      va1 = *(const uint4*)(vg1 + j0 + 64);
    }

    // S^T: sacc[i16][j16] row=j(quad*4+r), col=i(l16)
    v4f sacc[2][4];
#pragma unroll
    for (int i16 = 0; i16 < 2; ++i16)
#pragma unroll
      for (int j16 = 0; j16 < 4; ++j16) sacc[i16][j16] = zf;
    __builtin_amdgcn_s_setprio(1);
#pragma unroll
    for (int j16 = 0; j16 < 4; ++j16)
#pragma unroll
      for (int ks = 0; ks < 3; ++ks) {
        v8s kf = *(const v8s*)(kb + (j16 * 16 + l16) * 104 + ks * 32 + quad * 8);
        sacc[0][j16] = mfma16(kf, aq[0][ks], sacc[0][j16]);
        sacc[1][j16] = mfma16(kf, aq[1][ks], sacc[1][j16]);
      }
    __builtin_amdgcn_s_setprio(0);

    // exp2 (scores pre-scaled by log2e) + row-sum + pack via cvt_pk
#pragma unroll
    for (int i16 = 0; i16 < 2; ++i16)
#pragma unroll
      for (int j16 = 0; j16 < 4; ++j16) {
        float e0 = exp2fast(sacc[i16][j16][0]);
        float e1 = exp2fast(sacc[i16][j16][1]);
        float e2 = exp2fast(sacc[i16][j16][2]);
        float e3 = exp2fast(sacc[i16][j16][3]);
        l_acc[i16] += (e0 + e1) + (e2 + e3);
        uint2 pp;
        pp.x = cvtpk_bf16(e0, e1);
        pp.y = cvtpk_bf16(e2, e3);
        *(uint2*)&Ps[w][i16][l16][j16 * 16 + quad * 4] = pp;
      }

    // PV: P from per-wave LDS, V fragments from LDS tile
    __builtin_amdgcn_s_setprio(1);
#pragma unroll
    for (int jh = 0; jh < 2; ++jh) {
      v8s pf0 = *(const v8s*)&Ps[w][0][l16][jh * 32 + quad * 8];
      v8s pf1 = *(const v8s*)&Ps[w][1][l16][jh * 32 + quad * 8];
#pragma unroll
      for (int d16 = 0; d16 < 4; ++d16) {
        v8s vv = *(const v8s*)(vcur + (d16 * 16 + l16) * 72 + jh * 32 + quad * 8);
        oacc[0][d16] = mfma16(pf0, vv, oacc[0][d16]);
        oacc[1][d16] = mfma16(pf1, vv, oacc[1][d16]);
      }
    }
    __builtin_amdgcn_s_setprio(0);
    if (more) {
      u16* vwr = vsb + (cur ^ 1) * VSTRIDE;  // buffer read last iter; all waves past it
      *(uint4*)(vwr + vdo0) = va0;
      *(uint4*)(vwr + vdo1) = va1;
      __syncthreads();  // publishes K+V writes; protects dbufs
    }
  }

#pragma unroll
  for (int i16 = 0; i16 < 2; ++i16) {
    l_acc[i16] += __shfl_xor(l_acc[i16], 16, 64);
    l_acc[i16] += __shfl_xor(l_acc[i16], 32, 64);
    float linv = 1.f / l_acc[i16];
#pragma unroll
    for (int r = 0; r < 4; ++r) {
      float li = __shfl(linv, quad * 4 + r, 64);
      int ri = i0 + w * 32 + i16 * 16 + quad * 4 + r;
#pragma unroll
      for (int d16 = 0; d16 < 4; ++d16)
        At[((size_t)(b * 2048 + ri)) * 1024 + h * 64 + d16 * 16 + l16] = f2b(oacc[i16][d16][r] * li);
    }
    if (lane < 16) {
      size_t mbase = ((size_t)(b * 16 + h)) * 2048;
      lb[mbase + i0 + w * 32 + i16 * 16 + lane] = l_acc[i16];
    }
  }
}

// ---------------- pass 2: attn.mean over heads -> out1[B,L,L]; XCD-swizzled ----------------
// 1D grid 1024. XCD <- (b, i0-quad): per-XCD Qa slice 1.57 MB resident; the 4
// co-resident i0-blocks per j0 share each Ka tile -> Ka read ~once per XCD.
__global__ __launch_bounds__(256) void k_pass2(const u16* __restrict__ Qa, const u16* __restrict__ Ka,
                                               const float* __restrict__ lb,
                                               float* __restrict__ out1) {
  __shared__ __align__(16) u16 Ks[64][104];
  __shared__ float Ls[16][128];
  int t = threadIdx.x, w = t >> 6, lane = t & 63, quad = lane >> 4, l16 = lane & 15;
  int bid = blockIdx.x;
  int sem = ((bid & 7) << 7) | (bid >> 3);
  int xcd = sem >> 7;                                   // 0..7
  int b = xcd >> 2;                                     // 0..1
  int i0 = ((((xcd & 3) << 2) | (sem & 3))) << 7;       // 16 i-blocks * 128
  int j0 = ((sem >> 2) & 31) << 6;                      // 32 j-blocks * 64

#pragma unroll
  for (int rep = 0; rep < 8; ++rep) {
    int idx = t + rep * 256;
    int hh = idx >> 7, il = idx & 127;
    Ls[hh][il] = 0.0625f / lb[((size_t)(b * 16 + hh)) * 2048 + i0 + il];
  }

  size_t base0 = (size_t)b * 16 * 2048 * 96;
  const u16* kg[3]; u16* kd[3];
#pragma unroll
  for (int rep = 0; rep < 3; ++rep) {
    int idx = t + rep * 256;
    int r_ = idx / 12, c_ = idx % 12;
    kg[rep] = Ka + base0 + (size_t)(j0 + r_) * 96 + c_ * 8;
    kd[rep] = &Ks[r_][c_ * 8];
  }
  uint4 f0 = *(const uint4*)kg[0];
  uint4 f1 = *(const uint4*)kg[1];
  uint4 f2 = *(const uint4*)kg[2];

  const u16* q0 = Qa + base0 + (size_t)(i0 + w * 32 + l16) * 96 + quad * 8;
  const u16* q1 = q0 + 16 * 96;

  v4f zf = {0.f, 0.f, 0.f, 0.f};
  v4f macc[2][4];
#pragma unroll
  for (int i16 = 0; i16 < 2; ++i16)
#pragma unroll
    for (int j16 = 0; j16 < 4; ++j16) macc[i16][j16] = zf;

  v8s a[2][3];
#pragma unroll
  for (int ks = 0; ks < 3; ++ks) {
    a[0][ks] = *(const v8s*)(q0 + ks * 32);
    a[1][ks] = *(const v8s*)(q1 + ks * 32);
  }

  for (int h = 0; h < 16; ++h) {
    *(uint4*)kd[0] = f0;
    *(uint4*)kd[1] = f1;
    *(uint4*)kd[2] = f2;
    __syncthreads();
    if (h < 15) {
      kg[0] += 196608; kg[1] += 196608; kg[2] += 196608;
      f0 = *(const uint4*)kg[0];
      f1 = *(const uint4*)kg[1];
      f2 = *(const uint4*)kg[2];
    }

    v4f sacc[2][4];
#pragma unroll
    for (int i16 = 0; i16 < 2; ++i16)
#pragma unroll
      for (int j16 = 0; j16 < 4; ++j16) sacc[i16][j16] = zf;
#pragma unroll
    for (int ks = 0; ks < 3; ++ks)
#pragma unroll
      for (int j16 = 0; j16 < 4; ++j16) {
        v8s kf = *(const v8s*)&Ks[j16 * 16 + l16][ks * 32 + quad * 8];
        sacc[0][j16] = mfma16(a[0][ks], kf, sacc[0][j16]);
        sacc[1][j16] = mfma16(a[1][ks], kf, sacc[1][j16]);
      }

    if (h < 15) {
      q0 += 196608; q1 += 196608;
#pragma unroll
      for (int ks = 0; ks < 3; ++ks) {
        a[0][ks] = *(const v8s*)(q0 + ks * 32);
        a[1][ks] = *(const v8s*)(q1 + ks * 32);
      }
    }

    float li[2][4];
#pragma unroll
    for (int i16 = 0; i16 < 2; ++i16)
#pragma unroll
      for (int r = 0; r < 4; ++r)
        li[i16][r] = Ls[h][w * 32 + i16 * 16 + quad * 4 + r];
#pragma unroll
    for (int i16 = 0; i16 < 2; ++i16)
#pragma unroll
      for (int j16 = 0; j16 < 4; ++j16)
#pragma unroll
        for (int r = 0; r < 4; ++r)
          macc[i16][j16][r] += exp2fast(sacc[i16][j16][r]) * li[i16][r];
    __syncthreads();
  }

  float* o = out1 + (size_t)b * 2048 * 2048;
#pragma unroll
  for (int i16 = 0; i16 < 2; ++i16)
#pragma unroll
    for (int j16 = 0; j16 < 4; ++j16)
#pragma unroll
      for (int r = 0; r < 4; ++r)
        o[(size_t)(i0 + w * 32 + i16 * 16 + quad * 4 + r) * 2048 + j0 + j16 * 16 + l16] =
            macc[i16][j16][r];
}

extern "C" void kernel_launch(void* const* d_in, const int* in_sizes, int n_in,
                              void* d_out, int out_size, void* d_ws, size_t ws_size,
                              hipStream_t stream) {
  (void)in_sizes; (void)n_in; (void)out_size; (void)ws_size;
  const float* query = (const float*)d_in[0];
  const float* key_  = (const float*)d_in[1];
  const float* value = (const float*)d_in[2];
  const float* Wq = (const float*)d_in[3];
  const float* bq = (const float*)d_in[4];
  const float* Wk = (const float*)d_in[5];
  const float* bk = (const float*)d_in[6];
  const float* Wv = (const float*)d_in[7];
  const float* bv = (const float*)d_in[8];
  const float* Wo = (const float*)d_in[9];
  const float* bo = (const float*)d_in[10];
  const float* Wf = (const float*)d_in[11];
  const float* bff = (const float*)d_in[12];
  const float* qw = (const float*)d_in[13];
  const float* entp = (const float*)d_in[14];

  char* p = (char*)d_ws;
  u16* Xq  = (u16*)(p + 0);
  u16* Xk  = (u16*)(p + 8388608);
  u16* Xv  = (u16*)(p + 16777216);
  u16* Wqb = (u16*)(p + 25165824);
  u16* Wkb = (u16*)(p + 27262976);
  u16* Wvb = (u16*)(p + 29360128);
  u16* Qp  = (u16*)(p + 33554432);
  u16* Kp  = (u16*)(p + 41943040);
  u16* VtG = (u16*)(p + 50331648);
  u16* Qaa = (u16*)(p + 58720256);
  u16* Kaa = (u16*)(p + 71303168);
  float* lb = (float*)(p + 84148224);
  u16* At  = (u16*)(p + 84410368);
  u16* Wob = (u16*)(p + 31457280);

  // 1) fused converts (dst = ws[0 .. 33.5MB) contiguous)
  k_f2b_all<<<16384, 256, 0, stream>>>(query, key_, value, Wq, Wk, Wv, Wo, Xq);

  // 2) fused QKV projections (z: 0=Q rm, 1=K rm, 2=V -> V^T)
  k_gemm128<<<dim3(8, 32, 3), 256, 0, stream>>>(Xq, Xk, Xv, Wqb, Wkb, Wvb, bq, bk, bv,
                                                Qp, Kp, VtG, nullptr);

  // 3) augmented feature rows (fused Q+K; K-side carries log2e)
  k_features<<<dim3(256, 2), 256, 0, stream>>>(Qp, Kp, Wf, bff, qw, entp, Qaa, Kaa);

  // 4) flash pass 1 (R10 structure + V-in-LDS)
  k_flash<<<dim3(512), 256, 0, stream>>>(Qaa, Kaa, VtG, At, lb);

  // 5) head-mean of attention probs (XCD-swizzled 1D grid)
  k_pass2<<<dim3(1024), 256, 0, stream>>>(Qaa, Kaa, lb, (float*)d_out + 4194304);

  // 6) output projection -> fp32 d_out[0:4194304]
  k_gemm128<<<dim3(8, 32, 1), 256, 0, stream>>>(At, At, At, Wob, Wob, Wob, bo, bo, bo,
                                                nullptr, nullptr, nullptr, (float*)d_out);
}

// Round 6
// 330.213 us; speedup vs baseline: 1.3018x; 1.0018x over previous
//
#include <hip/hip_runtime.h>

// QuantumAttentionMechanism on MI355X (gfx950)
// B=2, L=2048, D=1024, H=16, hd=64, Q=8.
//
// Algebra: combined score = ((1-ent)*Qh.Kh + ent^2*(w*cos qq).cos kq + ent^2*(w*sin qq).sin kq)/8
//          -> single 96-dim (80 used) bf16 GEMM over augmented Q~/K~ rows.
// R12: occupancy fix for k_flash (R11 hit 63.5KB LDS -> 2 blocks/CU -> 2 waves/SIMD,
//     dependency-stall-bound). LDS diet to 51KB -> 3 blocks/CU: (a) Ps reused across
//     i16 (same-wave DS order makes the WAR safe), (b) V tile XOR-swizzled [2][64][64]
//     (reg-staged both sides; unit^=(row&7), 16B-aligned, ~2-way), (c) V frags hoisted
//     to regs once/iter. k_pass2: K dbuf across heads -> 1 barrier/head (was 2).
//     K path / exp2 / cvtpk / setprio / XCD swizzles = R11.
// Workspace layout (bytes), total ~92.8 MB:
//   Xq 0  Xk 8388608  Xv 16777216 | Wqb 25165824 Wkb 27262976 Wvb 29360128 Wob 31457280
//   Qp 33554432 Kp 41943040 VtG 50331648 | Qa 58720256 Ka 71303168
//   (unused) 83886080 lbuf 84148224 | At 84410368  (end 92798976)

typedef unsigned short u16;
typedef unsigned int u32;
typedef short v8s __attribute__((ext_vector_type(8)));
typedef float v4f __attribute__((ext_vector_type(4)));

static __device__ __forceinline__ float b2f(u16 h) {
  union { u32 u; float f; } a; a.u = ((u32)h) << 16; return a.f;
}
static __device__ __forceinline__ u16 f2b(float f) {
  union { float f; u32 u; } a; a.f = f;
  u32 u = a.u;
  u32 r = u + 0x7FFFu + ((u >> 16) & 1u);  // RNE
  return (u16)(r >> 16);
}
static __device__ __forceinline__ v4f mfma16(v8s a, v8s b, v4f c) {
  return __builtin_amdgcn_mfma_f32_16x16x32_bf16(a, b, c, 0, 0, 0);
}
// async global->LDS, 16B per lane; LDS dest = wave-uniform base + lane*16
static __device__ __forceinline__ void gload16(const u16* g, u16* l) {
  __builtin_amdgcn_global_load_lds((const __attribute__((address_space(1))) u32*)g,
                                   (__attribute__((address_space(3))) u32*)l, 16, 0, 0);
}
// 2^x via the native transcendental (scores are pre-scaled by log2(e))
static __device__ __forceinline__ float exp2fast(float x) {
  float r; asm("v_exp_f32 %0, %1" : "=v"(r) : "v"(x)); return r;
}
// pack two f32 -> [bf16(hi)|bf16(lo)]
static __device__ __forceinline__ u32 cvtpk_bf16(float lo, float hi) {
  u32 r; asm("v_cvt_pk_bf16_f32 %0, %1, %2" : "=v"(r) : "v"(lo), "v"(hi)); return r;
}

// ---------------- fused fp32 -> bf16 convert (all 7 arrays; dst region contiguous) ----------
__global__ __launch_bounds__(256) void k_f2b_all(const float* __restrict__ q, const float* __restrict__ k,
                                                 const float* __restrict__ v, const float* __restrict__ wq,
                                                 const float* __restrict__ wk, const float* __restrict__ wv,
                                                 const float* __restrict__ wo, u16* __restrict__ y) {
  int i = blockIdx.x * 256 + threadIdx.x;  // group of 4 elems; 4194304 total
  const float* src; int off;
  if (i < 1048576)      { src = q;  off = i; }
  else if (i < 2097152) { src = k;  off = i - 1048576; }
  else if (i < 3145728) { src = v;  off = i - 2097152; }
  else if (i < 3407872) { src = wq; off = i - 3145728; }
  else if (i < 3670016) { src = wk; off = i - 3407872; }
  else if (i < 3932160) { src = wv; off = i - 3670016; }
  else                  { src = wo; off = i - 3932160; }
  float4 val = ((const float4*)src)[off];
  union { u16 s[4]; uint2 u; } o;
  o.s[0] = f2b(val.x); o.s[1] = f2b(val.y); o.s[2] = f2b(val.z); o.s[3] = f2b(val.w);
  ((uint2*)y)[i] = o.u;
}

// ---------------- 128x128xBK64 GEMM, C = A[M,K]*B[N,K]^T + bias (M=4096,N=K=1024) --------
// BK=64 stored as two 32-elem halves (each the m97 conflict-free unpadded layout).
// blockIdx.z selects operand set. Epilogue: Cf -> fp32 rm; z<2 -> bf16 rm; z==2 -> V^T via LDS.
__global__ __launch_bounds__(256) void k_gemm128(
    const u16* __restrict__ A0, const u16* __restrict__ A1, const u16* __restrict__ A2,
    const u16* __restrict__ B0, const u16* __restrict__ B1, const u16* __restrict__ B2,
    const float* __restrict__ bias0, const float* __restrict__ bias1, const float* __restrict__ bias2,
    u16* __restrict__ O0, u16* __restrict__ O1, u16* __restrict__ O2t,
    float* __restrict__ Cf) {
  __shared__ __align__(16) u16 pool[18432];  // 36.9 KB: As|Bs (32KB) / Ts (34.8KB) aliased
  u16* As = pool;             // [kk][row][32] : kk*4096 + row*32 + c
  u16* Bs = pool + 8192;
  const int K = 1024, N = 1024;
  int t = threadIdx.x, w = t >> 6, lane = t & 63, quad = lane >> 4, l16 = lane & 15;
  int z = blockIdx.z;
  const u16* A = (z == 0) ? A0 : (z == 1) ? A1 : A2;
  const u16* Bm = (z == 0) ? B0 : (z == 1) ? B1 : B2;
  const float* bias = (z == 0) ? bias0 : (z == 1) ? bias1 : bias2;
  int n0 = blockIdx.x * 128, m0 = blockIdx.y * 128;

  // staging: 8 instrs/wave; q: mat=q>>2, kk=(q>>1)&1, rowgroup g=w+(q&1)*4
  int srow = lane >> 2, scol = (lane & 3) * 8;
  const u16* gp[8]; u16* lp[8];
#pragma unroll
  for (int qi = 0; qi < 8; ++qi) {
    int mat = qi >> 2, kk = (qi >> 1) & 1, g = w + (qi & 1) * 4;
    int row = g * 16 + srow;
    gp[qi] = (mat ? Bm + (size_t)(n0 + row) * K : A + (size_t)(m0 + row) * K) + kk * 32 + scol;
    lp[qi] = (mat ? Bs : As) + kk * 4096 + g * 512;
  }

  int mrow = (w >> 1) * 64, ncol = (w & 1) * 64;
  v4f zf = {0.f, 0.f, 0.f, 0.f};
  v4f acc[4][4];
#pragma unroll
  for (int mi = 0; mi < 4; ++mi)
#pragma unroll
    for (int ni = 0; ni < 4; ++ni) acc[mi][ni] = zf;

  for (int k0 = 0; k0 < K; k0 += 64) {
    __syncthreads();
#pragma unroll
    for (int qi = 0; qi < 8; ++qi) gload16(gp[qi] + k0, lp[qi]);
    __syncthreads();  // drains vmcnt
#pragma unroll
    for (int kk = 0; kk < 2; ++kk) {
      v8s af[4], bfr[4];
#pragma unroll
      for (int x = 0; x < 4; ++x) {
        af[x] = *(const v8s*)&As[kk * 4096 + (mrow + x * 16 + l16) * 32 + quad * 8];
        bfr[x] = *(const v8s*)&Bs[kk * 4096 + (ncol + x * 16 + l16) * 32 + quad * 8];
      }
#pragma unroll
      for (int mi = 0; mi < 4; ++mi)
#pragma unroll
        for (int ni = 0; ni < 4; ++ni)
          acc[mi][ni] = mfma16(af[mi], bfr[ni], acc[mi][ni]);
    }
  }

  float bv[4];
#pragma unroll
  for (int ni = 0; ni < 4; ++ni) bv[ni] = bias[n0 + ncol + ni * 16 + l16];

  if (Cf) {
#pragma unroll
    for (int mi = 0; mi < 4; ++mi)
#pragma unroll
      for (int ni = 0; ni < 4; ++ni)
#pragma unroll
        for (int r = 0; r < 4; ++r)
          Cf[(size_t)(m0 + mrow + mi * 16 + quad * 4 + r) * N + n0 + ncol + ni * 16 + l16] =
              acc[mi][ni][r] + bv[ni];
  } else if (z != 2) {
    u16* O = z ? O1 : O0;
#pragma unroll
    for (int mi = 0; mi < 4; ++mi)
#pragma unroll
      for (int ni = 0; ni < 4; ++ni)
#pragma unroll
        for (int r = 0; r < 4; ++r)
          O[(size_t)(m0 + mrow + mi * 16 + quad * 4 + r) * N + n0 + ncol + ni * 16 + l16] =
              f2b(acc[mi][ni][r] + bv[ni]);
  } else {
    // V^T: reuse pool as Ts[w][64][68]; wave-local write/read (same-wave DS order)
    __syncthreads();  // everyone done with As/Bs
    u16* Ts = pool + w * 64 * 68;
#pragma unroll
    for (int mi = 0; mi < 4; ++mi)
#pragma unroll
      for (int ni = 0; ni < 4; ++ni)
#pragma unroll
        for (int r = 0; r < 4; ++r)
          Ts[(mi * 16 + quad * 4 + r) * 68 + ni * 16 + l16] = f2b(acc[mi][ni][r] + bv[ni]);
    int c = lane;
    union { uint4 u[8]; u16 s[64]; } cb;
#pragma unroll
    for (int e = 0; e < 64; ++e) cb.s[e] = Ts[e * 68 + c];
    int bb = m0 >> 11, ml = m0 & 2047;
    u16* dst = O2t + ((size_t)(bb * 1024 + n0 + ncol + c)) * 2048 + ml + mrow;
#pragma unroll
    for (int e = 0; e < 8; ++e) *(uint4*)(dst + e * 8) = cb.u[e];
  }
}

// ---------------- build augmented Q~/K~ rows [B,H,L,96]; fused Q+K via blockIdx.y --------
// K-side scale carries log2(e) so the flash/pass2 exponential is a single v_exp_f32.
__global__ __launch_bounds__(256) void k_features(const u16* __restrict__ Qp, const u16* __restrict__ Kp,
                                                  const float* __restrict__ Wf, const float* __restrict__ bff,
                                                  const float* __restrict__ qw, const float* __restrict__ entp,
                                                  u16* __restrict__ Qaa, u16* __restrict__ Kaa) {
  int isK = blockIdx.y;
  const u16* P = isK ? Kp : Qp;
  u16* Out = isK ? Kaa : Qaa;
  int idx = blockIdx.x * 256 + threadIdx.x;  // 0..65535 = b*H*L + h*L + l
  int b = idx >> 15, h = (idx >> 11) & 15, l = idx & 2047;
  const u16* src = P + ((size_t)(b * 2048 + l)) * 1024 + h * 64;
  u16* dst = Out + (size_t)idx * 96;
  const float4* Wf4 = (const float4*)Wf;

  float x[64];
#pragma unroll
  for (int g = 0; g < 8; ++g) {
    union { uint4 u; u16 s[8]; } uu;
    uu.u = *(const uint4*)(src + g * 8);
#pragma unroll
    for (int e = 0; e < 8; ++e) x[g * 8 + e] = b2f(uu.s[e]);
  }
  float qv[8];
#pragma unroll
  for (int qq = 0; qq < 8; ++qq) qv[qq] = bff[qq];
#pragma unroll
  for (int d = 0; d < 64; ++d) {
    float4 wa = Wf4[d * 2], wb = Wf4[d * 2 + 1];
    float xd = x[d];
    qv[0] += xd * wa.x; qv[1] += xd * wa.y; qv[2] += xd * wa.z; qv[3] += xd * wa.w;
    qv[4] += xd * wb.x; qv[5] += xd * wb.y; qv[6] += xd * wb.z; qv[7] += xd * wb.w;
  }
  float cs[8], sn[8];
#pragma unroll
  for (int qq = 0; qq < 8; ++qq) {
    float e2 = __expf(2.f * qv[qq]);
    float th = 1.f - 2.f / (e2 + 1.f);  // tanh
    __sincosf(th, &sn[qq], &cs[qq]);
  }
  float ent = 1.f / (1.f + __expf(-entp[0]));
  union { uint4 u; u16 s[8]; } pc, ps;
  if (!isK) {
#pragma unroll
    for (int g = 0; g < 8; ++g) *(uint4*)(dst + g * 8) = *(const uint4*)(src + g * 8);
#pragma unroll
    for (int qq = 0; qq < 8; ++qq) {
      float sw = 1.f / (1.f + __expf(-qw[h * 8 + qq]));
      pc.s[qq] = f2b(cs[qq] * sw);
      ps.s[qq] = f2b(sn[qq] * sw);
    }
  } else {
    const float LOG2E = 1.44269504088896f;
    float c1 = (1.f - ent) * 0.125f * LOG2E, c2 = ent * ent * 0.125f * LOG2E;
#pragma unroll
    for (int g = 0; g < 8; ++g) {
      union { uint4 u; u16 s[8]; } ob;
#pragma unroll
      for (int e = 0; e < 8; ++e) ob.s[e] = f2b(x[g * 8 + e] * c1);
      *(uint4*)(dst + g * 8) = ob.u;
    }
#pragma unroll
    for (int qq = 0; qq < 8; ++qq) {
      pc.s[qq] = f2b(cs[qq] * c2);
      ps.s[qq] = f2b(sn[qq] * c2);
    }
  }
  *(uint4*)(dst + 64) = pc.u;
  *(uint4*)(dst + 72) = ps.u;
  uint4 z4 = {0, 0, 0, 0};
  *(uint4*)(dst + 80) = z4;
  *(uint4*)(dst + 88) = z4;
}

// ---------------- flash pass 1 (S^T, no-max): R11 structure, 51KB LDS -> 3 blocks/CU ----
// 4 waves x 32 i-rows (i-tile 128), K reg-staged dbuf (depth-2), V LDS dbuf XOR-swizzled
// [2][64][64] (reg-staged both sides), V frags hoisted to regs once/iter, Ps single
// buffer reused across i16 (same-wave DS ordering). XCD-swizzled 1D grid.
__global__ __launch_bounds__(256) void k_flash(const u16* __restrict__ Qa, const u16* __restrict__ Ka,
                                               const u16* __restrict__ VtG, u16* __restrict__ At,
                                               float* __restrict__ lb) {
  __shared__ __align__(16) u16 Ks[2][64][104];   // double-buffered K~ tile [j][k]   26624B
  __shared__ __align__(16) u16 Vs[2][4096];      // dbuf V^T tile [d][j] swizzled    16384B
  __shared__ __align__(16) u16 Ps[4][16][72];    // per-wave P, reused across i16     9216B

  int t = threadIdx.x, w = t >> 6, lane = t & 63, quad = lane >> 4, l16 = lane & 15;
  int bid = blockIdx.x;
  int sem = ((bid & 7) << 6) | (bid >> 3);  // XCD-contiguous semantic index
  int i0 = (sem & 15) << 7;                 // i-block (fastest within XCD -> L2 reuse)
  int hb = sem >> 4;                        // 0..31
  int h = hb & 15, b = hb >> 4;
  size_t qbase = ((size_t)(b * 16 + h)) * 2048 * 96;
  v8s aq[2][3];
#pragma unroll
  for (int i16 = 0; i16 < 2; ++i16) {
    const u16* Qrow = Qa + qbase + (size_t)(i0 + w * 32 + i16 * 16 + l16) * 96;
#pragma unroll
    for (int ks = 0; ks < 3; ++ks) aq[i16][ks] = *(const v8s*)(Qrow + ks * 32 + quad * 8);
  }
  const u16* Kbase = Ka + qbase;
  const u16* Vbase = VtG + ((size_t)(b * 1024 + h * 64)) * 2048;

  // K staging: 64x96 = 768 16B-groups, 3/thread
  const u16* kg[3]; int kdo[3];
#pragma unroll
  for (int p = 0; p < 3; ++p) {
    int idx = t + p * 256, r_ = idx / 12, c_ = idx % 12;
    kg[p] = Kbase + (size_t)r_ * 96 + c_ * 8;
    kdo[p] = r_ * 104 + c_ * 8;
  }
  u16* ks0 = &Ks[0][0][0];
  u16* ks1 = &Ks[1][0][0];

  // V staging: rows t>>3 and t>>3+32, unit t&7; XOR-swizzle unit ^= row&7 (rows 64 u16)
  {
  }
  int vrow = t >> 3, vunit = t & 7;
  const u16* vg0 = Vbase + (size_t)vrow * 2048 + vunit * 8;
  const u16* vg1 = vg0 + (size_t)32 * 2048;
  int vdo0 = vrow * 64 + (vunit ^ (vrow & 7)) * 8;
  int vdo1 = vdo0 + 32 * 64;   // row+32: same (row&7) -> same xor
  u16* vsb = &Vs[0][0];
  const int VSTRIDE = 4096;

  v4f zf = {0.f, 0.f, 0.f, 0.f};
  v4f oacc[2][4];
#pragma unroll
  for (int i16 = 0; i16 < 2; ++i16)
#pragma unroll
    for (int d16 = 0; d16 < 4; ++d16) oacc[i16][d16] = zf;
  float l_acc[2] = {0.f, 0.f};
  int lsw = l16 & 7;

  // prologue: stage K j=0 into buf0; K j=64 in regs; V j=0 into buf0
  uint4 fk0 = *(const uint4*)kg[0];
  uint4 fk1 = *(const uint4*)kg[1];
  uint4 fk2 = *(const uint4*)kg[2];
  kg[0] += 6144; kg[1] += 6144; kg[2] += 6144;
  *(uint4*)(ks0 + kdo[0]) = fk0;
  *(uint4*)(ks0 + kdo[1]) = fk1;
  *(uint4*)(ks0 + kdo[2]) = fk2;
  fk0 = *(const uint4*)kg[0];
  fk1 = *(const uint4*)kg[1];
  fk2 = *(const uint4*)kg[2];
  kg[0] += 6144; kg[1] += 6144; kg[2] += 6144;
  uint4 va0 = *(const uint4*)vg0;
  uint4 va1 = *(const uint4*)vg1;
  *(uint4*)(vsb + vdo0) = va0;
  *(uint4*)(vsb + vdo1) = va1;
  __syncthreads();

  for (int j0 = 0; j0 < 2048; j0 += 64) {
    int cur = (j0 >> 6) & 1;
    const u16* kb = cur ? ks1 : ks0;
    u16* kw = cur ? ks0 : ks1;
    const u16* vcur = vsb + cur * VSTRIDE;
    bool more = (j0 + 64) < 2048;
    if (more) {  // write next K tile (regs) into alternate buffer
      *(uint4*)(kw + kdo[0]) = fk0;
      *(uint4*)(kw + kdo[1]) = fk1;
      *(uint4*)(kw + kdo[2]) = fk2;
    }
    if (j0 + 128 < 2048) {  // prefetch next-next K tile
      fk0 = *(const uint4*)kg[0];
      fk1 = *(const uint4*)kg[1];
      fk2 = *(const uint4*)kg[2];
      kg[0] += 6144; kg[1] += 6144; kg[2] += 6144;
    }
    if (more) {  // issue next V tile loads (land during this iter's compute)
      va0 = *(const uint4*)(vg0 + j0 + 64);
      va1 = *(const uint4*)(vg1 + j0 + 64);
    }

    // S^T: sacc[i16][j16] row=j(quad*4+r), col=i(l16)
    v4f sacc[2][4];
#pragma unroll
    for (int i16 = 0; i16 < 2; ++i16)
#pragma unroll
      for (int j16 = 0; j16 < 4; ++j16) sacc[i16][j16] = zf;
    __builtin_amdgcn_s_setprio(1);
#pragma unroll
    for (int j16 = 0; j16 < 4; ++j16)
#pragma unroll
      for (int ks = 0; ks < 3; ++ks) {
        v8s kf = *(const v8s*)(kb + (j16 * 16 + l16) * 104 + ks * 32 + quad * 8);
        sacc[0][j16] = mfma16(kf, aq[0][ks], sacc[0][j16]);
        sacc[1][j16] = mfma16(kf, aq[1][ks], sacc[1][j16]);
      }
    __builtin_amdgcn_s_setprio(0);

    // V frags LDS -> regs once per iter (swizzled read; lgkm hides under exp2)
    v8s vf[8];
#pragma unroll
    for (int d16 = 0; d16 < 4; ++d16)
#pragma unroll
      for (int jh = 0; jh < 2; ++jh)
        vf[d16 * 2 + jh] =
            *(const v8s*)(vcur + (d16 * 16 + l16) * 64 + ((jh * 4 + quad) ^ lsw) * 8);

    // per-i16: exp2 + pack + Ps write, then PV (Ps buffer reused; same-wave DS order)
#pragma unroll
    for (int i16 = 0; i16 < 2; ++i16) {
#pragma unroll
      for (int j16 = 0; j16 < 4; ++j16) {
        float e0 = exp2fast(sacc[i16][j16][0]);
        float e1 = exp2fast(sacc[i16][j16][1]);
        float e2 = exp2fast(sacc[i16][j16][2]);
        float e3 = exp2fast(sacc[i16][j16][3]);
        l_acc[i16] += (e0 + e1) + (e2 + e3);
        uint2 pp;
        pp.x = cvtpk_bf16(e0, e1);
        pp.y = cvtpk_bf16(e2, e3);
        *(uint2*)&Ps[w][l16][j16 * 16 + quad * 4] = pp;
      }
      __builtin_amdgcn_s_setprio(1);
#pragma unroll
      for (int jh = 0; jh < 2; ++jh) {
        v8s pf = *(const v8s*)&Ps[w][l16][jh * 32 + quad * 8];
#pragma unroll
        for (int d16 = 0; d16 < 4; ++d16)
          oacc[i16][d16] = mfma16(pf, vf[d16 * 2 + jh], oacc[i16][d16]);
      }
      __builtin_amdgcn_s_setprio(0);
    }

    if (more) {
      u16* vwr = vsb + (cur ^ 1) * VSTRIDE;  // buffer read last iter; all waves past it
      *(uint4*)(vwr + vdo0) = va0;
      *(uint4*)(vwr + vdo1) = va1;
      __syncthreads();  // publishes K+V writes; protects dbufs
    }
  }

#pragma unroll
  for (int i16 = 0; i16 < 2; ++i16) {
    l_acc[i16] += __shfl_xor(l_acc[i16], 16, 64);
    l_acc[i16] += __shfl_xor(l_acc[i16], 32, 64);
    float linv = 1.f / l_acc[i16];
#pragma unroll
    for (int r = 0; r < 4; ++r) {
      float li = __shfl(linv, quad * 4 + r, 64);
      int ri = i0 + w * 32 + i16 * 16 + quad * 4 + r;
#pragma unroll
      for (int d16 = 0; d16 < 4; ++d16)
        At[((size_t)(b * 2048 + ri)) * 1024 + h * 64 + d16 * 16 + l16] = f2b(oacc[i16][d16][r] * li);
    }
    if (lane < 16) {
      size_t mbase = ((size_t)(b * 16 + h)) * 2048;
      lb[mbase + i0 + w * 32 + i16 * 16 + lane] = l_acc[i16];
    }
  }
}

// ---------------- pass 2: attn.mean over heads -> out1[B,L,L]; XCD-swizzled + K dbuf -----
// 1D grid 1024. XCD <- (b, i0-quad). K double-buffered across heads: 1 barrier/head.
__global__ __launch_bounds__(256) void k_pass2(const u16* __restrict__ Qa, const u16* __restrict__ Ka,
                                               const float* __restrict__ lb,
                                               float* __restrict__ out1) {
  __shared__ __align__(16) u16 Ks[2][64][104];
  __shared__ float Ls[16][128];
  int t = threadIdx.x, w = t >> 6, lane = t & 63, quad = lane >> 4, l16 = lane & 15;
  int bid = blockIdx.x;
  int sem = ((bid & 7) << 7) | (bid >> 3);
  int xcd = sem >> 7;                                   // 0..7
  int b = xcd >> 2;                                     // 0..1
  int i0 = ((((xcd & 3) << 2) | (sem & 3))) << 7;       // 16 i-blocks * 128
  int j0 = ((sem >> 2) & 31) << 6;                      // 32 j-blocks * 64

#pragma unroll
  for (int rep = 0; rep < 8; ++rep) {
    int idx = t + rep * 256;
    int hh = idx >> 7, il = idx & 127;
    Ls[hh][il] = 0.0625f / lb[((size_t)(b * 16 + hh)) * 2048 + i0 + il];
  }

  size_t base0 = (size_t)b * 16 * 2048 * 96;
  const u16* kg[3]; u16* kd[3];
#pragma unroll
  for (int rep = 0; rep < 3; ++rep) {
    int idx = t + rep * 256;
    int r_ = idx / 12, c_ = idx % 12;
    kg[rep] = Ka + base0 + (size_t)(j0 + r_) * 96 + c_ * 8;
    kd[rep] = &Ks[0][r_][c_ * 8];
  }
  const int KSTRIDE = 64 * 104;  // u16 per K buffer

  // prologue: stage h=0 into buf0; prefetch h=1 into regs
  uint4 f0 = *(const uint4*)kg[0];
  uint4 f1 = *(const uint4*)kg[1];
  uint4 f2 = *(const uint4*)kg[2];
  *(uint4*)kd[0] = f0; *(uint4*)kd[1] = f1; *(uint4*)kd[2] = f2;
  kg[0] += 196608; kg[1] += 196608; kg[2] += 196608;
  f0 = *(const uint4*)kg[0]; f1 = *(const uint4*)kg[1]; f2 = *(const uint4*)kg[2];

  const u16* q0 = Qa + base0 + (size_t)(i0 + w * 32 + l16) * 96 + quad * 8;
  const u16* q1 = q0 + 16 * 96;

  v4f zf = {0.f, 0.f, 0.f, 0.f};
  v4f macc[2][4];
#pragma unroll
  for (int i16 = 0; i16 < 2; ++i16)
#pragma unroll
    for (int j16 = 0; j16 < 4; ++j16) macc[i16][j16] = zf;

  v8s a[2][3];
#pragma unroll
  for (int ks = 0; ks < 3; ++ks) {
    a[0][ks] = *(const v8s*)(q0 + ks * 32);
    a[1][ks] = *(const v8s*)(q1 + ks * 32);
  }
  __syncthreads();  // Ls + buf0 ready

  for (int h = 0; h < 16; ++h) {
    if (h < 15) {  // write tile h+1 into alternate buffer (its readers barriered out)
      int aoff = ((h & 1) ^ 1) * KSTRIDE;
      *(uint4*)(kd[0] + aoff) = f0;
      *(uint4*)(kd[1] + aoff) = f1;
      *(uint4*)(kd[2] + aoff) = f2;
    }
    if (h < 14) {
      kg[0] += 196608; kg[1] += 196608; kg[2] += 196608;
      f0 = *(const uint4*)kg[0]; f1 = *(const uint4*)kg[1]; f2 = *(const uint4*)kg[2];
    }
    const u16* Kb = &Ks[h & 1][0][0];

    v4f sacc[2][4];
#pragma unroll
    for (int i16 = 0; i16 < 2; ++i16)
#pragma unroll
      for (int j16 = 0; j16 < 4; ++j16) sacc[i16][j16] = zf;
#pragma unroll
    for (int ks = 0; ks < 3; ++ks)
#pragma unroll
      for (int j16 = 0; j16 < 4; ++j16) {
        v8s kf = *(const v8s*)(Kb + (j16 * 16 + l16) * 104 + ks * 32 + quad * 8);
        sacc[0][j16] = mfma16(a[0][ks], kf, sacc[0][j16]);
        sacc[1][j16] = mfma16(a[1][ks], kf, sacc[1][j16]);
      }

    if (h < 15) {
      q0 += 196608; q1 += 196608;
#pragma unroll
      for (int ks = 0; ks < 3; ++ks) {
        a[0][ks] = *(const v8s*)(q0 + ks * 32);
        a[1][ks] = *(const v8s*)(q1 + ks * 32);
      }
    }

    float li[2][4];
#pragma unroll
    for (int i16 = 0; i16 < 2; ++i16)
#pragma unroll
      for (int r = 0; r < 4; ++r)
        li[i16][r] = Ls[h][w * 32 + i16 * 16 + quad * 4 + r];
#pragma unroll
    for (int i16 = 0; i16 < 2; ++i16)
#pragma unroll
      for (int j16 = 0; j16 < 4; ++j16)
#pragma unroll
        for (int r = 0; r < 4; ++r)
          macc[i16][j16][r] += exp2fast(sacc[i16][j16][r]) * li[i16][r];
    __syncthreads();  // readers done -> next iter may overwrite buf[h&1]
  }

  float* o = out1 + (size_t)b * 2048 * 2048;
#pragma unroll
  for (int i16 = 0; i16 < 2; ++i16)
#pragma unroll
    for (int j16 = 0; j16 < 4; ++j16)
#pragma unroll
      for (int r = 0; r < 4; ++r)
        o[(size_t)(i0 + w * 32 + i16 * 16 + quad * 4 + r) * 2048 + j0 + j16 * 16 + l16] =
            macc[i16][j16][r];
}

extern "C" void kernel_launch(void* const* d_in, const int* in_sizes, int n_in,
                              void* d_out, int out_size, void* d_ws, size_t ws_size,
                              hipStream_t stream) {
  (void)in_sizes; (void)n_in; (void)out_size; (void)ws_size;
  const float* query = (const float*)d_in[0];
  const float* key_  = (const float*)d_in[1];
  const float* value = (const float*)d_in[2];
  const float* Wq = (const float*)d_in[3];
  const float* bq = (const float*)d_in[4];
  const float* Wk = (const float*)d_in[5];
  const float* bk = (const float*)d_in[6];
  const float* Wv = (const float*)d_in[7];
  const float* bv = (const float*)d_in[8];
  const float* Wo = (const float*)d_in[9];
  const float* bo = (const float*)d_in[10];
  const float* Wf = (const float*)d_in[11];
  const float* bff = (const float*)d_in[12];
  const float* qw = (const float*)d_in[13];
  const float* entp = (const float*)d_in[14];

  char* p = (char*)d_ws;
  u16* Xq  = (u16*)(p + 0);
  u16* Xk  = (u16*)(p + 8388608);
  u16* Xv  = (u16*)(p + 16777216);
  u16* Wqb = (u16*)(p + 25165824);
  u16* Wkb = (u16*)(p + 27262976);
  u16* Wvb = (u16*)(p + 29360128);
  u16* Qp  = (u16*)(p + 33554432);
  u16* Kp  = (u16*)(p + 41943040);
  u16* VtG = (u16*)(p + 50331648);
  u16* Qaa = (u16*)(p + 58720256);
  u16* Kaa = (u16*)(p + 71303168);
  float* lb = (float*)(p + 84148224);
  u16* At  = (u16*)(p + 84410368);
  u16* Wob = (u16*)(p + 31457280);

  // 1) fused converts (dst = ws[0 .. 33.5MB) contiguous)
  k_f2b_all<<<16384, 256, 0, stream>>>(query, key_, value, Wq, Wk, Wv, Wo, Xq);

  // 2) fused QKV projections (z: 0=Q rm, 1=K rm, 2=V -> V^T)
  k_gemm128<<<dim3(8, 32, 3), 256, 0, stream>>>(Xq, Xk, Xv, Wqb, Wkb, Wvb, bq, bk, bv,
                                                Qp, Kp, VtG, nullptr);

  // 3) augmented feature rows (fused Q+K; K-side carries log2e)
  k_features<<<dim3(256, 2), 256, 0, stream>>>(Qp, Kp, Wf, bff, qw, entp, Qaa, Kaa);

  // 4) flash pass 1 (51KB LDS -> 3 blocks/CU)
  k_flash<<<dim3(512), 256, 0, stream>>>(Qaa, Kaa, VtG, At, lb);

  // 5) head-mean of attention probs (XCD-swizzled, K dbuf, 1 barrier/head)
  k_pass2<<<dim3(1024), 256, 0, stream>>>(Qaa, Kaa, lb, (float*)d_out + 4194304);

  // 6) output projection -> fp32 d_out[0:4194304]
  k_gemm128<<<dim3(8, 32, 1), 256, 0, stream>>>(At, At, At, Wob, Wob, Wob, bo, bo, bo,
                                                nullptr, nullptr, nullptr, (float*)d_out);
}